// Round 3
// baseline (13240.886 us; speedup 1.0000x reference)
//
#include <hip/hip_runtime.h>

typedef unsigned short u16;
typedef unsigned int u32;
typedef __bf16 bf16x8 __attribute__((ext_vector_type(8)));
typedef float f32x4 __attribute__((ext_vector_type(4)));

__device__ __forceinline__ float bf2f(u16 u) { return __uint_as_float(((u32)u) << 16); }
__device__ __forceinline__ u16 f2bf(float f) {
    u32 u = __float_as_uint(f);
    u32 r = (u + 0x7FFFu + ((u >> 16) & 1u)) >> 16;
    return (u16)r;
}
__device__ __forceinline__ float sigm(float x) { return 1.0f / (1.0f + __expf(-x)); }
__device__ __forceinline__ float elu1(float x) { return x > 0.0f ? x + 1.0f : __expf(x); }

// ---------------------------------------------------------------------------
// fp32 -> bf16 cast
// ---------------------------------------------------------------------------
__global__ __launch_bounds__(256) void k_f2b(const float* __restrict__ in,
                                             u16* __restrict__ out, int n4)
{
    int i = blockIdx.x * 256 + threadIdx.x;
    if (i < n4) {
        float4 v = ((const float4*)in)[i];
        ushort4 o;
        o.x = f2bf(v.x); o.y = f2bf(v.y); o.z = f2bf(v.z); o.w = f2bf(v.w);
        ((ushort4*)out)[i] = o;
    }
}

// ---------------------------------------------------------------------------
// Embedding: emb[row,:] = bf16(embed_W[tokens[row],:])  (row = t*64+b)
// ---------------------------------------------------------------------------
__global__ __launch_bounds__(256) void k_embed(const int* __restrict__ tok,
                                               const float* __restrict__ W,
                                               u16* __restrict__ out)
{
    int c = blockIdx.x * 256 + threadIdx.x;
    int row = c >> 5, cc = (c & 31) * 8;
    int t = tok[row];
    const float* src = W + (size_t)t * 256 + cc;
    u16 tmp[8];
#pragma unroll
    for (int k = 0; k < 8; k++) tmp[k] = f2bf(src[k]);
    *(uint4*)(out + (size_t)row * 256 + cc) = *(uint4*)tmp;
}

// ---------------------------------------------------------------------------
// GEMM:  C[M,N] = A[M,K](bf16, lda) * B[N,K]^T(bf16) + bias1 + bias2
// M = 32768, tile 128x128, BK=32, mfma 16x16x32 bf16. Out bf16 or fp32.
// ---------------------------------------------------------------------------
__global__ __launch_bounds__(256) void k_gemm_bt(
    const u16* __restrict__ A, int lda,
    const u16* __restrict__ B,
    u16* __restrict__ Cb, float* __restrict__ Cf, int ldc,
    const float* __restrict__ bias1, const float* __restrict__ bias2,
    int N, int K)
{
    __shared__ u16 As[128][40];
    __shared__ u16 Bs[128][40];
    const int tid = threadIdx.x;
    const int m0 = blockIdx.x * 128, n0 = blockIdx.y * 128;
    const int wave = tid >> 6, lane = tid & 63;
    const int wm = wave & 1, wn = wave >> 1;
    const int quad = lane >> 4, l16 = lane & 15;
    f32x4 acc[4][4] = {};
    for (int k0 = 0; k0 < K; k0 += 32) {
        __syncthreads();
#pragma unroll
        for (int i = 0; i < 2; i++) {
            int c = tid + i * 256, row = c >> 2, cc = (c & 3) * 8;
            *(uint4*)(&As[row][cc]) = *(const uint4*)(A + (size_t)(m0 + row) * lda + k0 + cc);
            uint4 d = {0, 0, 0, 0};
            if (n0 + row < N) d = *(const uint4*)(B + (size_t)(n0 + row) * K + k0 + cc);
            *(uint4*)(&Bs[row][cc]) = d;
        }
        __syncthreads();
        bf16x8 af[4], bfm[4];
#pragma unroll
        for (int x = 0; x < 4; x++) {
            af[x]  = *(const bf16x8*)(&As[wm * 64 + x * 16 + l16][quad * 8]);
            bfm[x] = *(const bf16x8*)(&Bs[wn * 64 + x * 16 + l16][quad * 8]);
        }
#pragma unroll
        for (int mi = 0; mi < 4; mi++)
#pragma unroll
            for (int ni = 0; ni < 4; ni++)
                acc[mi][ni] = __builtin_amdgcn_mfma_f32_16x16x32_bf16(af[mi], bfm[ni], acc[mi][ni], 0, 0, 0);
    }
#pragma unroll
    for (int ni = 0; ni < 4; ni++) {
        int col = n0 + wn * 64 + ni * 16 + l16;
        if (col < N) {
            float bv = 0.f;
            if (bias1) bv += bias1[col];
            if (bias2) bv += bias2[col];
#pragma unroll
            for (int mi = 0; mi < 4; mi++) {
                int r0 = m0 + wm * 64 + mi * 16 + quad * 4;
#pragma unroll
                for (int r = 0; r < 4; r++) {
                    float v = acc[mi][ni][r] + bv;
                    if (Cb) Cb[(size_t)(r0 + r) * ldc + col] = f2bf(v);
                    else    Cf[(size_t)(r0 + r) * ldc + col] = v;
                }
            }
        }
    }
}

// ---------------------------------------------------------------------------
// Contention-free grid barrier: per-block flag (own 64B line), wave0 polls.
// flags[i*16] holds last completed step of block i.
// ---------------------------------------------------------------------------
__device__ __forceinline__ void flag_barrier(int* flags, int step)
{
    __syncthreads();
    if (threadIdx.x == 0) {
        __threadfence();   // make this block's h-writes visible device-wide
        __hip_atomic_store(&flags[blockIdx.x * 16], step, __ATOMIC_RELEASE, __HIP_MEMORY_SCOPE_AGENT);
    }
    if (threadIdx.x < 64) {
        int i0 = threadIdx.x * 16, i1 = (threadIdx.x + 64) * 16;
        for (;;) {
            int v0 = __hip_atomic_load(&flags[i0], __ATOMIC_RELAXED, __HIP_MEMORY_SCOPE_AGENT);
            int v1 = __hip_atomic_load(&flags[i1], __ATOMIC_RELAXED, __HIP_MEMORY_SCOPE_AGENT);
            if (__all(v0 >= step && v1 >= step)) break;
            __builtin_amdgcn_s_sleep(1);
        }
    }
    __syncthreads();
    __threadfence();       // acquire side: invalidate stale cached lines
}

// ---------------------------------------------------------------------------
// Fused 2-layer persistent LSTM. 128 blocks x 256 threads.
// Blocks 0..63: layer 0 (x=emb, K=256). Blocks 64..127: layer 1 (x=h0 ring,
// K=512), lagging one global step. Block owns h-cols [jb, jb+8) -> 32 gate
// rows of Wih and Whh in LDS. Per step: z[64b x 32] = x@Wih^T + h@Whh^T via
// MFMA; elementwise c/h local; h through 4-slot global rings + flag barrier.
// ---------------------------------------------------------------------------
__global__ __launch_bounds__(256) void k_lstm2(
    const u16* __restrict__ emb,    // [32768,256] bf16
    const u16* __restrict__ Wx0,    // [2048,256] bf16
    const u16* __restrict__ Wh0,    // [2048,512] bf16
    const u16* __restrict__ Wx1,    // [2048,512] bf16
    const u16* __restrict__ Wh1,    // [2048,512] bf16
    const float* __restrict__ bi0, const float* __restrict__ bh0,
    const float* __restrict__ bi1, const float* __restrict__ bh1,
    u16* __restrict__ h0ring,       // [4][64][512] bf16
    u16* __restrict__ h1ring,       // [4][64][512] bf16
    u16* __restrict__ acat,         // [32768,544]; cols 0..511 = h1
    int* __restrict__ flags)
{
    __shared__ u16 Wx[32][520];
    __shared__ u16 Wh[32][520];
    __shared__ float zs[64][33];
    const int tid = threadIdx.x;
    const int layer = blockIdx.x >> 6;
    const int jbase = (blockIdx.x & 63) * 8;
    const int Kx = layer ? 512 : 256;
    const u16* Wxp = layer ? Wx1 : Wx0;
    const u16* Whp = layer ? Wh1 : Wh0;
    const float* bi = layer ? bi1 : bi0;
    const float* bh = layer ? bh1 : bh0;
    // Whh slice: 32 rows x 512
#pragma unroll
    for (int i = 0; i < 8; i++) {
        int c = tid + i * 256;
        int row = c >> 6, cc = (c & 63) * 8;
        int grow = (row >> 3) * 512 + jbase + (row & 7);
        *(uint4*)(&Wh[row][cc]) = *(const uint4*)(Whp + (size_t)grow * 512 + cc);
    }
    // Wih slice: 32 rows x Kx
    {
        int cpr = Kx >> 3;               // 8-elem chunks per row
        int iters = (32 * cpr) >> 8;     // 4 (K=256) or 8 (K=512)
        for (int i = 0; i < iters; i++) {
            int c = tid + i * 256;
            int row = c / cpr, cc = (c % cpr) * 8;
            int grow = (row >> 3) * 512 + jbase + (row & 7);
            *(uint4*)(&Wx[row][cc]) = *(const uint4*)(Wxp + (size_t)grow * Kx + cc);
        }
    }
    const int wave = tid >> 6, lane = tid & 63;
    const int quad = lane >> 4, l16 = lane & 15;
    const int m = wave * 16 + l16;
    const int pid0 = tid * 2,     b0 = pid0 >> 3, jj0 = pid0 & 7;
    const int pid1 = tid * 2 + 1, b1 = pid1 >> 3, jj1 = pid1 & 7;
    float bia0[4], bia1[4];
#pragma unroll
    for (int g = 0; g < 4; g++) {
        bia0[g] = bi[g * 512 + jbase + jj0] + bh[g * 512 + jbase + jj0];
        bia1[g] = bi[g * 512 + jbase + jj1] + bh[g * 512 + jbase + jj1];
    }
    u16* myring = layer ? h1ring : h0ring;
    float c0 = 0.f, c1 = 0.f;
    __syncthreads();
    for (int s = 0; s <= 512; s++) {
        const int active = layer ? (s >= 1) : (s < 512);
        const int t = layer ? (s - 1) : s;
        if (active) {
            f32x4 acc0 = {}, acc1 = {};
            // x contribution
            const u16* xrow = layer
                ? h0ring + ((size_t)(t & 3) * 64 + m) * 512
                : emb + ((size_t)t * 64 + m) * 256;
            const int nkc = Kx >> 5;
            for (int kc = 0; kc < nkc; kc++) {
                bf16x8 a  = *(const bf16x8*)(xrow + kc * 32 + quad * 8);
                bf16x8 w0 = *(const bf16x8*)(&Wx[l16][kc * 32 + quad * 8]);
                bf16x8 w1 = *(const bf16x8*)(&Wx[16 + l16][kc * 32 + quad * 8]);
                acc0 = __builtin_amdgcn_mfma_f32_16x16x32_bf16(a, w0, acc0, 0, 0, 0);
                acc1 = __builtin_amdgcn_mfma_f32_16x16x32_bf16(a, w1, acc1, 0, 0, 0);
            }
            // h contribution
            if (t > 0) {
                const u16* hrd = myring + (size_t)((t - 1) & 3) * 32768;
#pragma unroll
                for (int kc = 0; kc < 16; kc++) {
                    bf16x8 a  = *(const bf16x8*)(hrd + (size_t)m * 512 + kc * 32 + quad * 8);
                    bf16x8 w0 = *(const bf16x8*)(&Wh[l16][kc * 32 + quad * 8]);
                    bf16x8 w1 = *(const bf16x8*)(&Wh[16 + l16][kc * 32 + quad * 8]);
                    acc0 = __builtin_amdgcn_mfma_f32_16x16x32_bf16(a, w0, acc0, 0, 0, 0);
                    acc1 = __builtin_amdgcn_mfma_f32_16x16x32_bf16(a, w1, acc1, 0, 0, 0);
                }
            }
            int zb = wave * 16 + quad * 4;
#pragma unroll
            for (int r = 0; r < 4; r++) { zs[zb + r][l16] = acc0[r]; zs[zb + r][16 + l16] = acc1[r]; }
        }
        __syncthreads();
        if (active) {
            u16* hwr = myring + (size_t)(t & 3) * 32768;
            {
                float zi = zs[b0][jj0]      + bia0[0];
                float zf = zs[b0][8 + jj0]  + bia0[1];
                float zg = zs[b0][16 + jj0] + bia0[2];
                float zo = zs[b0][24 + jj0] + bia0[3];
                c0 = sigm(zf) * c0 + sigm(zi) * tanhf(zg);
                float h = sigm(zo) * tanhf(c0);
                u16 hb = f2bf(h);
                hwr[b0 * 512 + jbase + jj0] = hb;
                if (layer) acat[((size_t)t * 64 + b0) * 544 + jbase + jj0] = hb;
            }
            {
                float zi = zs[b1][jj1]      + bia1[0];
                float zf = zs[b1][8 + jj1]  + bia1[1];
                float zg = zs[b1][16 + jj1] + bia1[2];
                float zo = zs[b1][24 + jj1] + bia1[3];
                c1 = sigm(zf) * c1 + sigm(zi) * tanhf(zg);
                float h = sigm(zo) * tanhf(c1);
                u16 hb = f2bf(h);
                hwr[b1 * 512 + jbase + jj1] = hb;
                if (layer) acat[((size_t)t * 64 + b1) * 544 + jbase + jj1] = hb;
            }
        }
        flag_barrier(flags, s + 1);
    }
}

// ---------------------------------------------------------------------------
// Slot attention (eval). 8 positions/block, 32 lanes per position.
// ---------------------------------------------------------------------------
template <int NSLOT>
__global__ __launch_bounds__(256) void k_slot(
    const u16* __restrict__ dec,    // [32768,192] bf16
    const u16* __restrict__ initp,  // [32768, NSLOT*32] bf16
    const float* __restrict__ Wq, const float* __restrict__ bq,
    const float* __restrict__ Wk, const float* __restrict__ bk,
    const float* __restrict__ Wv, const float* __restrict__ bv,
    const float* __restrict__ lng, const float* __restrict__ lnb,
    const float* __restrict__ Wm1, const float* __restrict__ bm1,
    const float* __restrict__ Wm2, const float* __restrict__ bm2,
    const float* __restrict__ Wsp, const float* __restrict__ bsp,
    float* __restrict__ o1, float* __restrict__ o2, float* __restrict__ o3)
{
    __shared__ float WqT[32][33], WkT[64][33], WvT[64][33], Wm1T[32][65], Wm2T[64][33], WspT[64][33];
    __shared__ float bq_s[32], bk_s[32], bv_s[32], bm1_s[64], bm2_s[32], bsp_s[32], g_s[32], be_s[32];
    __shared__ u16 xbuf[8][192];
    __shared__ float slots[8][3][32], initl[8][3][32], kk[8][3][32], vv[8][3][32], qq[8][3][32];
    __shared__ float att[8][3][4];
    __shared__ float ubuf[8][32];
    __shared__ float hid[8][64];
    const int tid = threadIdx.x;
    for (int i = tid; i < 1024; i += 256) { int o = i >> 5, c = i & 31; WqT[c][o] = Wq[o * 32 + c]; }
    for (int i = tid; i < 2048; i += 256) {
        int o6 = i >> 6, c6 = i & 63;
        WkT[c6][o6]  = Wk[o6 * 64 + c6];
        WvT[c6][o6]  = Wv[o6 * 64 + c6];
        Wm2T[c6][o6] = Wm2[o6 * 64 + c6];
        WspT[c6][o6] = Wsp[o6 * 64 + c6];
        int o5 = i >> 5, c5 = i & 31;
        Wm1T[c5][o5] = Wm1[o5 * 32 + c5];
    }
    if (tid < 32) {
        bq_s[tid] = bq[tid]; bk_s[tid] = bk[tid]; bv_s[tid] = bv[tid];
        bm2_s[tid] = bm2[tid]; bsp_s[tid] = bsp[tid];
        g_s[tid] = lng[tid]; be_s[tid] = lnb[tid];
    }
    if (tid < 64) bm1_s[tid] = bm1[tid];
    const int p = tid >> 5, l = tid & 31;
    const size_t row = (size_t)blockIdx.x * 8 + p;
    for (int i = l; i < 192; i += 32) xbuf[p][i] = dec[row * 192 + i];
    __syncthreads();

#pragma unroll
    for (int i = 0; i < 3; i++) {
        float aK = bk_s[l], aV = bv_s[l];
        for (int c = 0; c < 64; c++) {
            float x = bf2f(xbuf[p][i * 64 + c]);
            aK += x * WkT[c][l];
            aV += x * WvT[c][l];
        }
        kk[p][i][l] = elu1(aK);
        vv[p][i][l] = aV;
    }
#pragma unroll
    for (int j = 0; j < NSLOT; j++) {
        float iv = bf2f(initp[row * (NSLOT * 32) + j * 32 + l]);
        initl[p][j][l] = iv;
        slots[p][j][l] = iv;
    }
    __syncthreads();
    const float rs = 0.17677669529663687f;  // 32^-0.5
    for (int it = 0; it < 3; it++) {
#pragma unroll
        for (int j = 0; j < NSLOT; j++) {
            float a = bq_s[l];
            for (int c = 0; c < 32; c++) a += slots[p][j][c] * WqT[c][l];
            qq[p][j][l] = elu1((a + initl[p][j][l]) * rs);
        }
        __syncthreads();
        if (l < 3 * NSLOT) {
            int i = l / NSLOT, j = l % NSLOT;
            float s = 0.f;
            for (int c = 0; c < 32; c++) s += kk[p][i][c] * qq[p][j][c];
            att[p][i][j] = s;
        }
        __syncthreads();
        if (l < 3) {
            float mx = -1e30f;
            for (int j = 0; j < NSLOT; j++) mx = fmaxf(mx, att[p][l][j]);
            float sm = 0.f, ex[NSLOT];
            for (int j = 0; j < NSLOT; j++) { ex[j] = __expf(att[p][l][j] - mx); sm += ex[j]; }
            for (int j = 0; j < NSLOT; j++) att[p][l][j] = ex[j] / sm + 1e-8f;
        }
        __syncthreads();
        if (l < NSLOT) {
            float s = att[p][0][l] + att[p][1][l] + att[p][2][l];
            float inv = 1.0f / s;
            for (int i = 0; i < 3; i++) att[p][i][l] *= inv;
        }
        __syncthreads();
#pragma unroll
        for (int j = 0; j < NSLOT; j++) {
            float u = att[p][0][j] * vv[p][0][l] + att[p][1][j] * vv[p][1][l] + att[p][2][j] * vv[p][2][l];
            float mean = u;
            for (int mk = 1; mk < 32; mk <<= 1) mean += __shfl_xor(mean, mk, 32);
            mean *= (1.0f / 32.0f);
            float d = u - mean;
            float var = d * d;
            for (int mk = 1; mk < 32; mk <<= 1) var += __shfl_xor(var, mk, 32);
            var *= (1.0f / 32.0f);
            float y = d * rsqrtf(var + 1e-5f) * g_s[l] + be_s[l];
            ubuf[p][l] = y;
            __syncthreads();
#pragma unroll
            for (int oo = 0; oo < 2; oo++) {
                int o = l + oo * 32;
                float a = bm1_s[o];
                for (int c = 0; c < 32; c++) a += ubuf[p][c] * Wm1T[c][o];
                hid[p][o] = fmaxf(a, 0.f);
            }
            __syncthreads();
            float a2 = bm2_s[l];
            for (int c = 0; c < 64; c++) a2 += hid[p][c] * Wm2T[c][l];
            slots[p][j][l] += a2 * (1.0f / 32.0f);
            __syncthreads();
        }
    }
    float pj[NSLOT];
#pragma unroll
    for (int j = 0; j < NSLOT; j++) {
        float a = bsp_s[l];
        for (int c = 0; c < 32; c++) a += initl[p][j][c] * WspT[c][l];
        for (int c = 0; c < 32; c++) a += slots[p][j][c] * WspT[32 + c][l];
        pj[j] = a;
    }
    const float e = 1e-6f, me = (float)(1.0 - 2e-6);
    if (NSLOT == 3) {
        o1[row * 32 + l] = tanhf(me * pj[0] + e * pj[1] + e * pj[2]);
        o2[row * 32 + l] = tanhf(e * pj[0] + me * pj[1] + e * pj[2]);
        o3[row * 32 + l] = tanhf(e * pj[0] + e * pj[1] + me * pj[2]);
    } else {
        o1[row * 32 + l] = tanhf(me * pj[0] + e * pj[1]);
        o2[row * 32 + l] = tanhf(e * pj[0] + me * pj[1]);
    }
}

// ---------------------------------------------------------------------------
// gate[row] = sigmoid(h1[row,:512] . Wg + bg + 1). One wave per row.
// ---------------------------------------------------------------------------
__global__ __launch_bounds__(256) void k_gate(
    const u16* __restrict__ acat, const float* __restrict__ Wg,
    const float* __restrict__ bg, float* __restrict__ gate)
{
    const int row = blockIdx.x * 4 + (threadIdx.x >> 6);
    const int lane = threadIdx.x & 63;
    const u16* h = acat + (size_t)row * 544;
    float s = 0.f;
    for (int c = lane; c < 512; c += 64) s += bf2f(h[c]) * Wg[c];
    for (int mk = 1; mk < 64; mk <<= 1) s += __shfl_xor(s, mk, 64);
    if (lane == 0) gate[row] = sigm(s + bg[0] + 1.0f);
}

// ---------------------------------------------------------------------------
// Memory scan. One block per batch b; mem[32][32][32] fp32 in registers.
// ---------------------------------------------------------------------------
__global__ __launch_bounds__(256) void k_scan(
    const float* __restrict__ r1, const float* __restrict__ r2,
    const float* __restrict__ fi, const float* __restrict__ uu1,
    const float* __restrict__ uu2, const float* __restrict__ gg,
    u16* __restrict__ acat)
{
    const int b = blockIdx.x, tid = threadIdx.x;
    const int f = tid & 31, rg = tid >> 5;
    float m[4][32];
#pragma unroll
    for (int x = 0; x < 4; x++)
        for (int y = 0; y < 32; y++) m[x][y] = 0.f;
    __shared__ float r1s[32], r2s[32], fis[32], u1s[32], u2s[32];
    __shared__ float red[8][32];
    __shared__ float wred[4];
    __shared__ float gsh;
    for (int t = 0; t < 512; t++) {
        size_t base = ((size_t)t * 64 + b) * 32;
        if (tid < 32) r1s[tid] = r1[base + tid];
        else if (tid < 64) r2s[tid - 32] = r2[base + tid - 32];
        else if (tid < 96) fis[tid - 64] = fi[base + tid - 64];
        else if (tid < 128) u1s[tid - 96] = uu1[base + tid - 96];
        else if (tid < 160) u2s[tid - 128] = uu2[base + tid - 128];
        else if (tid == 160) gsh = gg[t * 64 + b];
        __syncthreads();
        float p = 0.f;
#pragma unroll
        for (int rl = 0; rl < 4; rl++) {
            float s = 0.f;
            for (int ti = 0; ti < 32; ti++) s += r2s[ti] * m[rl][ti];
            p += r1s[rg * 4 + rl] * s;
        }
        red[rg][f] = p;
        __syncthreads();
        float prev = 0.f;
#pragma unroll
        for (int g = 0; g < 8; g++) prev += red[g][f];
        float curo = gsh * (fis[f] - prev) * (1.0f / 32.0f);
        float nsq = 0.f;
#pragma unroll
        for (int rl = 0; rl < 4; rl++) {
            float a = r1s[rg * 4 + rl] * curo;
            for (int ti = 0; ti < 32; ti++) {
                m[rl][ti] += a * r2s[ti];
                nsq += m[rl][ti] * m[rl][ti];
            }
        }
        for (int mk = 1; mk < 64; mk <<= 1) nsq += __shfl_xor(nsq, mk, 64);
        __syncthreads();
        if ((tid & 63) == 0) wred[tid >> 6] = nsq;
        __syncthreads();
        float nrm = sqrtf(wred[0] + wred[1] + wred[2] + wred[3]);
        float sc = nrm > 1.0f ? 1.0f / nrm : 1.0f;   // relu(nrm-1)+1 == max(nrm,1)
        float rp = 0.f;
#pragma unroll
        for (int rl = 0; rl < 4; rl++) {
            float s = 0.f;
            for (int ti = 0; ti < 32; ti++) {
                m[rl][ti] *= sc;
                s += m[rl][ti] * u2s[ti];
            }
            rp += u1s[rg * 4 + rl] * s;
        }
        red[rg][f] = rp;
        __syncthreads();
        float rv = 0.f;
#pragma unroll
        for (int g = 0; g < 8; g++) rv += red[g][f];
        float mean = rv;
        for (int mk = 1; mk < 32; mk <<= 1) mean += __shfl_xor(mean, mk, 32);
        mean *= (1.0f / 32.0f);
        float d = rv - mean;
        float var = d * d;
        for (int mk = 1; mk < 32; mk <<= 1) var += __shfl_xor(var, mk, 32);
        var *= (1.0f / 32.0f);
        if (tid < 32) {
            float y = d * rsqrtf(var + 1e-5f);
            acat[((size_t)t * 64 + b) * 544 + 512 + f] = f2bf(y);
        }
        __syncthreads();
    }
}

// ---------------------------------------------------------------------------
extern "C" void kernel_launch(void* const* d_in, const int* in_sizes, int n_in,
                              void* d_out, int out_size, void* d_ws, size_t ws_size,
                              hipStream_t stream)
{
    (void)in_sizes; (void)n_in; (void)out_size; (void)ws_size;
    const int*   tokens = (const int*)d_in[0];
    const float* embW  = (const float*)d_in[1];
    const float* Wih0  = (const float*)d_in[2];
    const float* Whh0  = (const float*)d_in[3];
    const float* bih0  = (const float*)d_in[4];
    const float* bhh0  = (const float*)d_in[5];
    const float* Wih1  = (const float*)d_in[6];
    const float* Whh1  = (const float*)d_in[7];
    const float* bih1  = (const float*)d_in[8];
    const float* bhh1  = (const float*)d_in[9];
    const float* Wpi   = (const float*)d_in[10];
    const float* bpi   = (const float*)d_in[11];
    const float* Wq    = (const float*)d_in[12];
    const float* bq    = (const float*)d_in[13];
    const float* Wk    = (const float*)d_in[14];
    const float* bk    = (const float*)d_in[15];
    const float* Wv    = (const float*)d_in[16];
    const float* bv    = (const float*)d_in[17];
    const float* lng   = (const float*)d_in[18];
    const float* lnb   = (const float*)d_in[19];
    const float* Wm1   = (const float*)d_in[20];
    const float* bm1   = (const float*)d_in[21];
    const float* Wm2   = (const float*)d_in[22];
    const float* bm2   = (const float*)d_in[23];
    const float* Wbind = (const float*)d_in[24];
    const float* bbind = (const float*)d_in[25];
    const float* Wreas = (const float*)d_in[26];
    const float* breas = (const float*)d_in[27];
    const float* Wsp   = (const float*)d_in[28];
    const float* bsp   = (const float*)d_in[29];
    const float* Wg    = (const float*)d_in[30];
    const float* bg    = (const float*)d_in[31];
    const float* Wout  = (const float*)d_in[32];
    const float* bout  = (const float*)d_in[33];

    // workspace (~105 MB total)
    char* ws = (char*)d_ws;
    size_t off = 0;
    auto alloc = [&](size_t bytes) { size_t o = off; off += (bytes + 255) & ~(size_t)255; return o; };
    int*  flags  = (int*)(ws + alloc(128 * 64));
    u16*  emb    = (u16*)(ws + alloc(32768ull * 256 * 2));
    u16*  dec    = (u16*)(ws + alloc(32768ull * 192 * 2));
    u16*  initb  = (u16*)(ws + alloc(32768ull * 96 * 2));
    u16*  initr  = (u16*)(ws + alloc(32768ull * 64 * 2));
    u16*  acat   = (u16*)(ws + alloc(32768ull * 544 * 2));    // [h1(512) | reads(32)]
    u16*  h0ring = (u16*)(ws + alloc(4ull * 64 * 512 * 2));
    u16*  h1ring = (u16*)(ws + alloc(4ull * 64 * 512 * 2));
    float* role1 = (float*)(ws + alloc(32768ull * 32 * 4));
    float* role2 = (float*)(ws + alloc(32768ull * 32 * 4));
    float* fill  = (float*)(ws + alloc(32768ull * 32 * 4));
    float* u1v   = (float*)(ws + alloc(32768ull * 32 * 4));
    float* u2v   = (float*)(ws + alloc(32768ull * 32 * 4));
    float* gatev = (float*)(ws + alloc(32768ull * 4));
    u16* Wx0b  = (u16*)(ws + alloc(2048ull * 256 * 2));
    u16* Wh0b  = (u16*)(ws + alloc(2048ull * 512 * 2));
    u16* Wx1b  = (u16*)(ws + alloc(2048ull * 512 * 2));
    u16* Wh1b  = (u16*)(ws + alloc(2048ull * 512 * 2));
    u16* Wpib  = (u16*)(ws + alloc(192ull * 256 * 2));
    u16* Wbindb = (u16*)(ws + alloc(96ull * 192 * 2));
    u16* Wreasb = (u16*)(ws + alloc(64ull * 192 * 2));
    u16* Woutb  = (u16*)(ws + alloc(128ull * 544 * 2));

    hipMemsetAsync(flags, 0, 128 * 64, stream);
    auto cvt = [&](const float* src, u16* dst, int n) {
        k_f2b<<<(n / 4 + 255) / 256, 256, 0, stream>>>(src, dst, n / 4);
    };
    cvt(Wih0, Wx0b, 2048 * 256);
    cvt(Whh0, Wh0b, 2048 * 512);
    cvt(Wih1, Wx1b, 2048 * 512);
    cvt(Whh1, Wh1b, 2048 * 512);
    cvt(Wpi,  Wpib,  192 * 256);
    cvt(Wbind, Wbindb, 96 * 192);
    cvt(Wreas, Wreasb, 64 * 192);
    cvt(Wout, Woutb, 128 * 544);

    k_embed<<<4096, 256, 0, stream>>>(tokens, embW, emb);
    // dec_in = emb @ Wpi^T + bpi
    k_gemm_bt<<<dim3(256, 2), 256, 0, stream>>>(emb, 256, Wpib, dec, nullptr, 192, bpi, nullptr, 192, 256);
    // slot inits
    k_gemm_bt<<<dim3(256, 1), 256, 0, stream>>>(dec, 192, Wbindb, initb, nullptr, 96, bbind, nullptr, 96, 192);
    k_gemm_bt<<<dim3(256, 1), 256, 0, stream>>>(dec, 192, Wreasb, initr, nullptr, 64, breas, nullptr, 64, 192);
    // fused 2-layer LSTM (h1 -> acat cols 0..511)
    k_lstm2<<<128, 256, 0, stream>>>(emb, Wx0b, Wh0b, Wx1b, Wh1b,
                                     bih0, bhh0, bih1, bhh1,
                                     h0ring, h1ring, acat, flags);
    // slot attention
    k_slot<3><<<4096, 256, 0, stream>>>(dec, initb, Wq, bq, Wk, bk, Wv, bv, lng, lnb,
                                        Wm1, bm1, Wm2, bm2, Wsp, bsp, role1, role2, fill);
    k_slot<2><<<4096, 256, 0, stream>>>(dec, initr, Wq, bq, Wk, bk, Wv, bv, lng, lnb,
                                        Wm1, bm1, Wm2, bm2, Wsp, bsp, u1v, u2v, nullptr);
    k_gate<<<8192, 256, 0, stream>>>(acat, Wg, bg, gatev);
    k_scan<<<64, 256, 0, stream>>>(role1, role2, fill, u1v, u2v, gatev, acat);
    // out = acat @ Wout^T + bout  (fp32 output)
    k_gemm_bt<<<dim3(256, 1), 256, 0, stream>>>(acat, 544, Woutb, nullptr, (float*)d_out, 128, bout, nullptr, 128, 544);
}

// Round 4
// 7386.092 us; speedup vs baseline: 1.7927x; 1.7927x over previous
//
#include <hip/hip_runtime.h>

typedef unsigned short u16;
typedef unsigned int u32;
typedef unsigned long long u64;
typedef __bf16 bf16x8 __attribute__((ext_vector_type(8)));
typedef float f32x4 __attribute__((ext_vector_type(4)));

__device__ __forceinline__ float bf2f(u16 u) { return __uint_as_float(((u32)u) << 16); }
__device__ __forceinline__ u16 f2bf(float f) {
    u32 u = __float_as_uint(f);
    u32 r = (u + 0x7FFFu + ((u >> 16) & 1u)) >> 16;
    return (u16)r;
}
__device__ __forceinline__ float sigm(float x) { return 1.0f / (1.0f + __expf(-x)); }
__device__ __forceinline__ float elu1(float x) { return x > 0.0f ? x + 1.0f : __expf(x); }

// LLC-coherent (agent-scope, relaxed) accessors: bypass non-coherent per-XCD L2.
__device__ __forceinline__ bf16x8 llc_load8(const u16* p) {
    union { u64 q[2]; bf16x8 v; } c;
    c.q[0] = __hip_atomic_load((const u64*)p,       __ATOMIC_RELAXED, __HIP_MEMORY_SCOPE_AGENT);
    c.q[1] = __hip_atomic_load((const u64*)(p + 4), __ATOMIC_RELAXED, __HIP_MEMORY_SCOPE_AGENT);
    return c.v;
}
__device__ __forceinline__ void llc_store2(u16* p, u16 a, u16 b) {
    u32 v = (u32)a | ((u32)b << 16);
    __hip_atomic_store((u32*)p, v, __ATOMIC_RELAXED, __HIP_MEMORY_SCOPE_AGENT);
}

// ---------------------------------------------------------------------------
// fp32 -> bf16 cast
// ---------------------------------------------------------------------------
__global__ __launch_bounds__(256) void k_f2b(const float* __restrict__ in,
                                             u16* __restrict__ out, int n4)
{
    int i = blockIdx.x * 256 + threadIdx.x;
    if (i < n4) {
        float4 v = ((const float4*)in)[i];
        ushort4 o;
        o.x = f2bf(v.x); o.y = f2bf(v.y); o.z = f2bf(v.z); o.w = f2bf(v.w);
        ((ushort4*)out)[i] = o;
    }
}

// ---------------------------------------------------------------------------
// Embedding: emb[row,:] = bf16(embed_W[tokens[row],:])  (row = t*64+b)
// ---------------------------------------------------------------------------
__global__ __launch_bounds__(256) void k_embed(const int* __restrict__ tok,
                                               const float* __restrict__ W,
                                               u16* __restrict__ out)
{
    int c = blockIdx.x * 256 + threadIdx.x;
    int row = c >> 5, cc = (c & 31) * 8;
    int t = tok[row];
    const float* src = W + (size_t)t * 256 + cc;
    u16 tmp[8];
#pragma unroll
    for (int k = 0; k < 8; k++) tmp[k] = f2bf(src[k]);
    *(uint4*)(out + (size_t)row * 256 + cc) = *(uint4*)tmp;
}

// ---------------------------------------------------------------------------
// GEMM:  C[M,N] = A[M,K](bf16, lda) * B[N,K]^T(bf16) + bias1 + bias2
// M = 32768, tile 128x128, BK=32, mfma 16x16x32 bf16. Out bf16 or fp32.
// ---------------------------------------------------------------------------
__global__ __launch_bounds__(256) void k_gemm_bt(
    const u16* __restrict__ A, int lda,
    const u16* __restrict__ B,
    u16* __restrict__ Cb, float* __restrict__ Cf, int ldc,
    const float* __restrict__ bias1, const float* __restrict__ bias2,
    int N, int K)
{
    __shared__ u16 As[128][40];
    __shared__ u16 Bs[128][40];
    const int tid = threadIdx.x;
    const int m0 = blockIdx.x * 128, n0 = blockIdx.y * 128;
    const int wave = tid >> 6, lane = tid & 63;
    const int wm = wave & 1, wn = wave >> 1;
    const int quad = lane >> 4, l16 = lane & 15;
    f32x4 acc[4][4] = {};
    for (int k0 = 0; k0 < K; k0 += 32) {
        __syncthreads();
#pragma unroll
        for (int i = 0; i < 2; i++) {
            int c = tid + i * 256, row = c >> 2, cc = (c & 3) * 8;
            *(uint4*)(&As[row][cc]) = *(const uint4*)(A + (size_t)(m0 + row) * lda + k0 + cc);
            uint4 d = {0, 0, 0, 0};
            if (n0 + row < N) d = *(const uint4*)(B + (size_t)(n0 + row) * K + k0 + cc);
            *(uint4*)(&Bs[row][cc]) = d;
        }
        __syncthreads();
        bf16x8 af[4], bfm[4];
#pragma unroll
        for (int x = 0; x < 4; x++) {
            af[x]  = *(const bf16x8*)(&As[wm * 64 + x * 16 + l16][quad * 8]);
            bfm[x] = *(const bf16x8*)(&Bs[wn * 64 + x * 16 + l16][quad * 8]);
        }
#pragma unroll
        for (int mi = 0; mi < 4; mi++)
#pragma unroll
            for (int ni = 0; ni < 4; ni++)
                acc[mi][ni] = __builtin_amdgcn_mfma_f32_16x16x32_bf16(af[mi], bfm[ni], acc[mi][ni], 0, 0, 0);
    }
#pragma unroll
    for (int ni = 0; ni < 4; ni++) {
        int col = n0 + wn * 64 + ni * 16 + l16;
        if (col < N) {
            float bv = 0.f;
            if (bias1) bv += bias1[col];
            if (bias2) bv += bias2[col];
#pragma unroll
            for (int mi = 0; mi < 4; mi++) {
                int r0 = m0 + wm * 64 + mi * 16 + quad * 4;
#pragma unroll
                for (int r = 0; r < 4; r++) {
                    float v = acc[mi][ni][r] + bv;
                    if (Cb) Cb[(size_t)(r0 + r) * ldc + col] = f2bf(v);
                    else    Cf[(size_t)(r0 + r) * ldc + col] = v;
                }
            }
        }
    }
}

// ---------------------------------------------------------------------------
// Fused 2-layer persistent LSTM, fence-free LLC handshake.
// 128 blocks x 256 threads. Blocks 0..63: layer 0 (x=emb, K=256).
// Blocks 64..127: layer 1 (x=h0 ring, K=512). Depth-4 h rings; per-layer
// flag groups; all cross-block data via agent-scope relaxed atomics (LLC).
// Layer 0 at t needs: own f0 >= t, other f1 >= t-3 (ring overwrite guard).
// Layer 1 at t needs: other f0 >= t+1 (h0[t] ready), own f1 >= t.
// ---------------------------------------------------------------------------
__global__ __launch_bounds__(256) void k_lstm2(
    const u16* __restrict__ emb,    // [32768,256] bf16
    const u16* __restrict__ Wx0,    // [2048,256] bf16
    const u16* __restrict__ Wh0,    // [2048,512] bf16
    const u16* __restrict__ Wx1,    // [2048,512] bf16
    const u16* __restrict__ Wh1,    // [2048,512] bf16
    const float* __restrict__ bi0, const float* __restrict__ bh0,
    const float* __restrict__ bi1, const float* __restrict__ bh1,
    u16* __restrict__ h0ring,       // [4][64][512] bf16
    u16* __restrict__ h1ring,       // [4][64][512] bf16
    u16* __restrict__ acat,         // [32768,544]; cols 0..511 = h1
    int* __restrict__ flags)        // [2][64][16] ints
{
    __shared__ u16 Wx[32][520];
    __shared__ u16 Wh[32][520];
    __shared__ float zs[64][33];
    const int tid = threadIdx.x;
    const int layer = blockIdx.x >> 6;
    const int me = blockIdx.x & 63;
    const int jbase = me * 8;
    const int Kx = layer ? 512 : 256;
    const u16* Wxp = layer ? Wx1 : Wx0;
    const u16* Whp = layer ? Wh1 : Wh0;
    const float* bi = layer ? bi1 : bi0;
    const float* bh = layer ? bh1 : bh0;
    // Whh slice: 32 gate rows x 512
#pragma unroll
    for (int i = 0; i < 8; i++) {
        int c = tid + i * 256;
        int row = c >> 6, cc = (c & 63) * 8;
        int grow = (row >> 3) * 512 + jbase + (row & 7);
        *(uint4*)(&Wh[row][cc]) = *(const uint4*)(Whp + (size_t)grow * 512 + cc);
    }
    // Wih slice: 32 gate rows x Kx
    {
        int cpr = Kx >> 3;
        int iters = (32 * cpr) >> 8;
        for (int i = 0; i < iters; i++) {
            int c = tid + i * 256;
            int row = c / cpr, cc = (c % cpr) * 8;
            int grow = (row >> 3) * 512 + jbase + (row & 7);
            *(uint4*)(&Wx[row][cc]) = *(const uint4*)(Wxp + (size_t)grow * Kx + cc);
        }
    }
    const int wave = tid >> 6, lane = tid & 63;
    const int quad = lane >> 4, l16 = lane & 15;
    const int m = wave * 16 + l16;
    const int b = tid >> 2, jj = (tid & 3) * 2;   // this thread: batch b, cols jj,jj+1
    float bia0[4], bia1[4];
#pragma unroll
    for (int g = 0; g < 4; g++) {
        bia0[g] = bi[g * 512 + jbase + jj]     + bh[g * 512 + jbase + jj];
        bia1[g] = bi[g * 512 + jbase + jj + 1] + bh[g * 512 + jbase + jj + 1];
    }
    int* fown = flags + layer * 1024;          // [64][16]
    int* foth = flags + (1 - layer) * 1024;
    u16* myring = layer ? h1ring : h0ring;
    float c0 = 0.f, c1 = 0.f;
    __syncthreads();
    for (int t = 0; t < 512; t++) {
        const int needOwn = t;
        const int needOth = layer ? t + 1 : t - 3;
        if (tid < 64) {
            int* po = fown + tid * 16;
            int* px = foth + tid * 16;
            for (;;) {
                int a = __hip_atomic_load(po, __ATOMIC_RELAXED, __HIP_MEMORY_SCOPE_AGENT);
                int c = __hip_atomic_load(px, __ATOMIC_RELAXED, __HIP_MEMORY_SCOPE_AGENT);
                if (__all(a >= needOwn && c >= needOth)) break;
                __builtin_amdgcn_s_sleep(1);
            }
        }
        __syncthreads();
        f32x4 acc0 = {}, acc1 = {};
        // x contribution
        if (layer) {
            const u16* xrow = h0ring + ((size_t)(t & 3) * 64 + m) * 512;
#pragma unroll
            for (int kc = 0; kc < 16; kc++) {
                bf16x8 a  = llc_load8(xrow + kc * 32 + quad * 8);
                bf16x8 w0 = *(const bf16x8*)(&Wx[l16][kc * 32 + quad * 8]);
                bf16x8 w1 = *(const bf16x8*)(&Wx[16 + l16][kc * 32 + quad * 8]);
                acc0 = __builtin_amdgcn_mfma_f32_16x16x32_bf16(a, w0, acc0, 0, 0, 0);
                acc1 = __builtin_amdgcn_mfma_f32_16x16x32_bf16(a, w1, acc1, 0, 0, 0);
            }
        } else {
            const u16* xrow = emb + ((size_t)t * 64 + m) * 256;
#pragma unroll
            for (int kc = 0; kc < 8; kc++) {
                bf16x8 a  = *(const bf16x8*)(xrow + kc * 32 + quad * 8);
                bf16x8 w0 = *(const bf16x8*)(&Wx[l16][kc * 32 + quad * 8]);
                bf16x8 w1 = *(const bf16x8*)(&Wx[16 + l16][kc * 32 + quad * 8]);
                acc0 = __builtin_amdgcn_mfma_f32_16x16x32_bf16(a, w0, acc0, 0, 0, 0);
                acc1 = __builtin_amdgcn_mfma_f32_16x16x32_bf16(a, w1, acc1, 0, 0, 0);
            }
        }
        // h contribution
        if (t > 0) {
            const u16* hrd = myring + (size_t)((t - 1) & 3) * 32768 + (size_t)m * 512;
#pragma unroll
            for (int kc = 0; kc < 16; kc++) {
                bf16x8 a  = llc_load8(hrd + kc * 32 + quad * 8);
                bf16x8 w0 = *(const bf16x8*)(&Wh[l16][kc * 32 + quad * 8]);
                bf16x8 w1 = *(const bf16x8*)(&Wh[16 + l16][kc * 32 + quad * 8]);
                acc0 = __builtin_amdgcn_mfma_f32_16x16x32_bf16(a, w0, acc0, 0, 0, 0);
                acc1 = __builtin_amdgcn_mfma_f32_16x16x32_bf16(a, w1, acc1, 0, 0, 0);
            }
        }
        {
            int zb = wave * 16 + quad * 4;
#pragma unroll
            for (int r = 0; r < 4; r++) { zs[zb + r][l16] = acc0[r]; zs[zb + r][16 + l16] = acc1[r]; }
        }
        __syncthreads();
        {
            u16* hwr = myring + (size_t)(t & 3) * 32768;
            float zi0 = zs[b][jj]      + bia0[0];
            float zf0 = zs[b][8 + jj]  + bia0[1];
            float zg0 = zs[b][16 + jj] + bia0[2];
            float zo0 = zs[b][24 + jj] + bia0[3];
            c0 = sigm(zf0) * c0 + sigm(zi0) * tanhf(zg0);
            float h0v = sigm(zo0) * tanhf(c0);
            float zi1 = zs[b][jj + 1]      + bia1[0];
            float zf1 = zs[b][8 + jj + 1]  + bia1[1];
            float zg1 = zs[b][16 + jj + 1] + bia1[2];
            float zo1 = zs[b][24 + jj + 1] + bia1[3];
            c1 = sigm(zf1) * c1 + sigm(zi1) * tanhf(zg1);
            float h1v = sigm(zo1) * tanhf(c1);
            u16 hb0 = f2bf(h0v), hb1 = f2bf(h1v);
            llc_store2(hwr + b * 512 + jbase + jj, hb0, hb1);
            if (layer)
                *(u32*)(acat + ((size_t)t * 64 + b) * 544 + jbase + jj) = (u32)hb0 | ((u32)hb1 << 16);
        }
        __syncthreads();   // drains every wave's vmcnt -> h stores acked at LLC
        if (tid == 0)
            __hip_atomic_store(fown + me * 16, t + 1, __ATOMIC_RELAXED, __HIP_MEMORY_SCOPE_AGENT);
    }
}

// ---------------------------------------------------------------------------
// Slot attention (eval). 8 positions/block, 32 lanes per position.
// ---------------------------------------------------------------------------
template <int NSLOT>
__global__ __launch_bounds__(256) void k_slot(
    const u16* __restrict__ dec,    // [32768,192] bf16
    const u16* __restrict__ initp,  // [32768, NSLOT*32] bf16
    const float* __restrict__ Wq, const float* __restrict__ bq,
    const float* __restrict__ Wk, const float* __restrict__ bk,
    const float* __restrict__ Wv, const float* __restrict__ bv,
    const float* __restrict__ lng, const float* __restrict__ lnb,
    const float* __restrict__ Wm1, const float* __restrict__ bm1,
    const float* __restrict__ Wm2, const float* __restrict__ bm2,
    const float* __restrict__ Wsp, const float* __restrict__ bsp,
    float* __restrict__ o1, float* __restrict__ o2, float* __restrict__ o3)
{
    __shared__ float WqT[32][33], WkT[64][33], WvT[64][33], Wm1T[32][65], Wm2T[64][33], WspT[64][33];
    __shared__ float bq_s[32], bk_s[32], bv_s[32], bm1_s[64], bm2_s[32], bsp_s[32], g_s[32], be_s[32];
    __shared__ u16 xbuf[8][192];
    __shared__ float slots[8][3][32], initl[8][3][32], kk[8][3][32], vv[8][3][32], qq[8][3][32];
    __shared__ float att[8][3][4];
    __shared__ float ubuf[8][32];
    __shared__ float hid[8][64];
    const int tid = threadIdx.x;
    for (int i = tid; i < 1024; i += 256) { int o = i >> 5, c = i & 31; WqT[c][o] = Wq[o * 32 + c]; }
    for (int i = tid; i < 2048; i += 256) {
        int o6 = i >> 6, c6 = i & 63;
        WkT[c6][o6]  = Wk[o6 * 64 + c6];
        WvT[c6][o6]  = Wv[o6 * 64 + c6];
        Wm2T[c6][o6] = Wm2[o6 * 64 + c6];
        WspT[c6][o6] = Wsp[o6 * 64 + c6];
        int o5 = i >> 5, c5 = i & 31;
        Wm1T[c5][o5] = Wm1[o5 * 32 + c5];
    }
    if (tid < 32) {
        bq_s[tid] = bq[tid]; bk_s[tid] = bk[tid]; bv_s[tid] = bv[tid];
        bm2_s[tid] = bm2[tid]; bsp_s[tid] = bsp[tid];
        g_s[tid] = lng[tid]; be_s[tid] = lnb[tid];
    }
    if (tid < 64) bm1_s[tid] = bm1[tid];
    const int p = tid >> 5, l = tid & 31;
    const size_t row = (size_t)blockIdx.x * 8 + p;
    for (int i = l; i < 192; i += 32) xbuf[p][i] = dec[row * 192 + i];
    __syncthreads();

#pragma unroll
    for (int i = 0; i < 3; i++) {
        float aK = bk_s[l], aV = bv_s[l];
        for (int c = 0; c < 64; c++) {
            float x = bf2f(xbuf[p][i * 64 + c]);
            aK += x * WkT[c][l];
            aV += x * WvT[c][l];
        }
        kk[p][i][l] = elu1(aK);
        vv[p][i][l] = aV;
    }
#pragma unroll
    for (int j = 0; j < NSLOT; j++) {
        float iv = bf2f(initp[row * (NSLOT * 32) + j * 32 + l]);
        initl[p][j][l] = iv;
        slots[p][j][l] = iv;
    }
    __syncthreads();
    const float rs = 0.17677669529663687f;  // 32^-0.5
    for (int it = 0; it < 3; it++) {
#pragma unroll
        for (int j = 0; j < NSLOT; j++) {
            float a = bq_s[l];
            for (int c = 0; c < 32; c++) a += slots[p][j][c] * WqT[c][l];
            qq[p][j][l] = elu1((a + initl[p][j][l]) * rs);
        }
        __syncthreads();
        if (l < 3 * NSLOT) {
            int i = l / NSLOT, j = l % NSLOT;
            float s = 0.f;
            for (int c = 0; c < 32; c++) s += kk[p][i][c] * qq[p][j][c];
            att[p][i][j] = s;
        }
        __syncthreads();
        if (l < 3) {
            float mx = -1e30f;
            for (int j = 0; j < NSLOT; j++) mx = fmaxf(mx, att[p][l][j]);
            float sm = 0.f, ex[NSLOT];
            for (int j = 0; j < NSLOT; j++) { ex[j] = __expf(att[p][l][j] - mx); sm += ex[j]; }
            for (int j = 0; j < NSLOT; j++) att[p][l][j] = ex[j] / sm + 1e-8f;
        }
        __syncthreads();
        if (l < NSLOT) {
            float s = att[p][0][l] + att[p][1][l] + att[p][2][l];
            float inv = 1.0f / s;
            for (int i = 0; i < 3; i++) att[p][i][l] *= inv;
        }
        __syncthreads();
#pragma unroll
        for (int j = 0; j < NSLOT; j++) {
            float u = att[p][0][j] * vv[p][0][l] + att[p][1][j] * vv[p][1][l] + att[p][2][j] * vv[p][2][l];
            float mean = u;
            for (int mk = 1; mk < 32; mk <<= 1) mean += __shfl_xor(mean, mk, 32);
            mean *= (1.0f / 32.0f);
            float d = u - mean;
            float var = d * d;
            for (int mk = 1; mk < 32; mk <<= 1) var += __shfl_xor(var, mk, 32);
            var *= (1.0f / 32.0f);
            float y = d * rsqrtf(var + 1e-5f) * g_s[l] + be_s[l];
            ubuf[p][l] = y;
            __syncthreads();
#pragma unroll
            for (int oo = 0; oo < 2; oo++) {
                int o = l + oo * 32;
                float a = bm1_s[o];
                for (int c = 0; c < 32; c++) a += ubuf[p][c] * Wm1T[c][o];
                hid[p][o] = fmaxf(a, 0.f);
            }
            __syncthreads();
            float a2 = bm2_s[l];
            for (int c = 0; c < 64; c++) a2 += hid[p][c] * Wm2T[c][l];
            slots[p][j][l] += a2 * (1.0f / 32.0f);
            __syncthreads();
        }
    }
    float pj[NSLOT];
#pragma unroll
    for (int j = 0; j < NSLOT; j++) {
        float a = bsp_s[l];
        for (int c = 0; c < 32; c++) a += initl[p][j][c] * WspT[c][l];
        for (int c = 0; c < 32; c++) a += slots[p][j][c] * WspT[32 + c][l];
        pj[j] = a;
    }
    const float e = 1e-6f, me = (float)(1.0 - 2e-6);
    if (NSLOT == 3) {
        o1[row * 32 + l] = tanhf(me * pj[0] + e * pj[1] + e * pj[2]);
        o2[row * 32 + l] = tanhf(e * pj[0] + me * pj[1] + e * pj[2]);
        o3[row * 32 + l] = tanhf(e * pj[0] + e * pj[1] + me * pj[2]);
    } else {
        o1[row * 32 + l] = tanhf(me * pj[0] + e * pj[1]);
        o2[row * 32 + l] = tanhf(e * pj[0] + me * pj[1]);
    }
}

// ---------------------------------------------------------------------------
// gate[row] = sigmoid(h1[row,:512] . Wg + bg + 1). One wave per row.
// ---------------------------------------------------------------------------
__global__ __launch_bounds__(256) void k_gate(
    const u16* __restrict__ acat, const float* __restrict__ Wg,
    const float* __restrict__ bg, float* __restrict__ gate)
{
    const int row = blockIdx.x * 4 + (threadIdx.x >> 6);
    const int lane = threadIdx.x & 63;
    const u16* h = acat + (size_t)row * 544;
    float s = 0.f;
    for (int c = lane; c < 512; c += 64) s += bf2f(h[c]) * Wg[c];
    for (int mk = 1; mk < 64; mk <<= 1) s += __shfl_xor(s, mk, 64);
    if (lane == 0) gate[row] = sigm(s + bg[0] + 1.0f);
}

// ---------------------------------------------------------------------------
// Memory scan. One block per batch b; mem[32][32][32] fp32 in registers.
// ---------------------------------------------------------------------------
__global__ __launch_bounds__(256) void k_scan(
    const float* __restrict__ r1, const float* __restrict__ r2,
    const float* __restrict__ fi, const float* __restrict__ uu1,
    const float* __restrict__ uu2, const float* __restrict__ gg,
    u16* __restrict__ acat)
{
    const int b = blockIdx.x, tid = threadIdx.x;
    const int f = tid & 31, rg = tid >> 5;
    float m[4][32];
#pragma unroll
    for (int x = 0; x < 4; x++)
        for (int y = 0; y < 32; y++) m[x][y] = 0.f;
    __shared__ float r1s[32], r2s[32], fis[32], u1s[32], u2s[32];
    __shared__ float red[8][32];
    __shared__ float wred[4];
    __shared__ float gsh;
    for (int t = 0; t < 512; t++) {
        size_t base = ((size_t)t * 64 + b) * 32;
        if (tid < 32) r1s[tid] = r1[base + tid];
        else if (tid < 64) r2s[tid - 32] = r2[base + tid - 32];
        else if (tid < 96) fis[tid - 64] = fi[base + tid - 64];
        else if (tid < 128) u1s[tid - 96] = uu1[base + tid - 96];
        else if (tid < 160) u2s[tid - 128] = uu2[base + tid - 128];
        else if (tid == 160) gsh = gg[t * 64 + b];
        __syncthreads();
        float p = 0.f;
#pragma unroll
        for (int rl = 0; rl < 4; rl++) {
            float s = 0.f;
            for (int ti = 0; ti < 32; ti++) s += r2s[ti] * m[rl][ti];
            p += r1s[rg * 4 + rl] * s;
        }
        red[rg][f] = p;
        __syncthreads();
        float prev = 0.f;
#pragma unroll
        for (int g = 0; g < 8; g++) prev += red[g][f];
        float curo = gsh * (fis[f] - prev) * (1.0f / 32.0f);
        float nsq = 0.f;
#pragma unroll
        for (int rl = 0; rl < 4; rl++) {
            float a = r1s[rg * 4 + rl] * curo;
            for (int ti = 0; ti < 32; ti++) {
                m[rl][ti] += a * r2s[ti];
                nsq += m[rl][ti] * m[rl][ti];
            }
        }
        for (int mk = 1; mk < 64; mk <<= 1) nsq += __shfl_xor(nsq, mk, 64);
        __syncthreads();
        if ((tid & 63) == 0) wred[tid >> 6] = nsq;
        __syncthreads();
        float nrm = sqrtf(wred[0] + wred[1] + wred[2] + wred[3]);
        float sc = nrm > 1.0f ? 1.0f / nrm : 1.0f;   // relu(nrm-1)+1 == max(nrm,1)
        float rp = 0.f;
#pragma unroll
        for (int rl = 0; rl < 4; rl++) {
            float s = 0.f;
            for (int ti = 0; ti < 32; ti++) {
                m[rl][ti] *= sc;
                s += m[rl][ti] * u2s[ti];
            }
            rp += u1s[rg * 4 + rl] * s;
        }
        red[rg][f] = rp;
        __syncthreads();
        float rv = 0.f;
#pragma unroll
        for (int g = 0; g < 8; g++) rv += red[g][f];
        float mean = rv;
        for (int mk = 1; mk < 32; mk <<= 1) mean += __shfl_xor(mean, mk, 32);
        mean *= (1.0f / 32.0f);
        float d = rv - mean;
        float var = d * d;
        for (int mk = 1; mk < 32; mk <<= 1) var += __shfl_xor(var, mk, 32);
        var *= (1.0f / 32.0f);
        if (tid < 32) {
            float y = d * rsqrtf(var + 1e-5f);
            acat[((size_t)t * 64 + b) * 544 + 512 + f] = f2bf(y);
        }
        __syncthreads();
    }
}

// ---------------------------------------------------------------------------
extern "C" void kernel_launch(void* const* d_in, const int* in_sizes, int n_in,
                              void* d_out, int out_size, void* d_ws, size_t ws_size,
                              hipStream_t stream)
{
    (void)in_sizes; (void)n_in; (void)out_size; (void)ws_size;
    const int*   tokens = (const int*)d_in[0];
    const float* embW  = (const float*)d_in[1];
    const float* Wih0  = (const float*)d_in[2];
    const float* Whh0  = (const float*)d_in[3];
    const float* bih0  = (const float*)d_in[4];
    const float* bhh0  = (const float*)d_in[5];
    const float* Wih1  = (const float*)d_in[6];
    const float* Whh1  = (const float*)d_in[7];
    const float* bih1  = (const float*)d_in[8];
    const float* bhh1  = (const float*)d_in[9];
    const float* Wpi   = (const float*)d_in[10];
    const float* bpi   = (const float*)d_in[11];
    const float* Wq    = (const float*)d_in[12];
    const float* bq    = (const float*)d_in[13];
    const float* Wk    = (const float*)d_in[14];
    const float* bk    = (const float*)d_in[15];
    const float* Wv    = (const float*)d_in[16];
    const float* bv    = (const float*)d_in[17];
    const float* lng   = (const float*)d_in[18];
    const float* lnb   = (const float*)d_in[19];
    const float* Wm1   = (const float*)d_in[20];
    const float* bm1   = (const float*)d_in[21];
    const float* Wm2   = (const float*)d_in[22];
    const float* bm2   = (const float*)d_in[23];
    const float* Wbind = (const float*)d_in[24];
    const float* bbind = (const float*)d_in[25];
    const float* Wreas = (const float*)d_in[26];
    const float* breas = (const float*)d_in[27];
    const float* Wsp   = (const float*)d_in[28];
    const float* bsp   = (const float*)d_in[29];
    const float* Wg    = (const float*)d_in[30];
    const float* bg    = (const float*)d_in[31];
    const float* Wout  = (const float*)d_in[32];
    const float* bout  = (const float*)d_in[33];

    // workspace (~105 MB total)
    char* ws = (char*)d_ws;
    size_t off = 0;
    auto alloc = [&](size_t bytes) { size_t o = off; off += (bytes + 255) & ~(size_t)255; return o; };
    int*  flags  = (int*)(ws + alloc(2 * 64 * 16 * 4));
    u16*  emb    = (u16*)(ws + alloc(32768ull * 256 * 2));
    u16*  dec    = (u16*)(ws + alloc(32768ull * 192 * 2));
    u16*  initb  = (u16*)(ws + alloc(32768ull * 96 * 2));
    u16*  initr  = (u16*)(ws + alloc(32768ull * 64 * 2));
    u16*  acat   = (u16*)(ws + alloc(32768ull * 544 * 2));    // [h1(512) | reads(32)]
    u16*  h0ring = (u16*)(ws + alloc(4ull * 64 * 512 * 2));
    u16*  h1ring = (u16*)(ws + alloc(4ull * 64 * 512 * 2));
    float* role1 = (float*)(ws + alloc(32768ull * 32 * 4));
    float* role2 = (float*)(ws + alloc(32768ull * 32 * 4));
    float* fill  = (float*)(ws + alloc(32768ull * 32 * 4));
    float* u1v   = (float*)(ws + alloc(32768ull * 32 * 4));
    float* u2v   = (float*)(ws + alloc(32768ull * 32 * 4));
    float* gatev = (float*)(ws + alloc(32768ull * 4));
    u16* Wx0b  = (u16*)(ws + alloc(2048ull * 256 * 2));
    u16* Wh0b  = (u16*)(ws + alloc(2048ull * 512 * 2));
    u16* Wx1b  = (u16*)(ws + alloc(2048ull * 512 * 2));
    u16* Wh1b  = (u16*)(ws + alloc(2048ull * 512 * 2));
    u16* Wpib  = (u16*)(ws + alloc(192ull * 256 * 2));
    u16* Wbindb = (u16*)(ws + alloc(96ull * 192 * 2));
    u16* Wreasb = (u16*)(ws + alloc(64ull * 192 * 2));
    u16* Woutb  = (u16*)(ws + alloc(128ull * 544 * 2));

    hipMemsetAsync(flags, 0, 2 * 64 * 16 * 4, stream);
    auto cvt = [&](const float* src, u16* dst, int n) {
        k_f2b<<<(n / 4 + 255) / 256, 256, 0, stream>>>(src, dst, n / 4);
    };
    cvt(Wih0, Wx0b, 2048 * 256);
    cvt(Whh0, Wh0b, 2048 * 512);
    cvt(Wih1, Wx1b, 2048 * 512);
    cvt(Whh1, Wh1b, 2048 * 512);
    cvt(Wpi,  Wpib,  192 * 256);
    cvt(Wbind, Wbindb, 96 * 192);
    cvt(Wreas, Wreasb, 64 * 192);
    cvt(Wout, Woutb, 128 * 544);

    k_embed<<<4096, 256, 0, stream>>>(tokens, embW, emb);
    // dec_in = emb @ Wpi^T + bpi
    k_gemm_bt<<<dim3(256, 2), 256, 0, stream>>>(emb, 256, Wpib, dec, nullptr, 192, bpi, nullptr, 192, 256);
    // slot inits
    k_gemm_bt<<<dim3(256, 1), 256, 0, stream>>>(dec, 192, Wbindb, initb, nullptr, 96, bbind, nullptr, 96, 192);
    k_gemm_bt<<<dim3(256, 1), 256, 0, stream>>>(dec, 192, Wreasb, initr, nullptr, 64, breas, nullptr, 64, 192);
    // fused 2-layer LSTM (h1 -> acat cols 0..511)
    k_lstm2<<<128, 256, 0, stream>>>(emb, Wx0b, Wh0b, Wx1b, Wh1b,
                                     bih0, bhh0, bih1, bhh1,
                                     h0ring, h1ring, acat, flags);
    // slot attention
    k_slot<3><<<4096, 256, 0, stream>>>(dec, initb, Wq, bq, Wk, bk, Wv, bv, lng, lnb,
                                        Wm1, bm1, Wm2, bm2, Wsp, bsp, role1, role2, fill);
    k_slot<2><<<4096, 256, 0, stream>>>(dec, initr, Wq, bq, Wk, bk, Wv, bv, lng, lnb,
                                        Wm1, bm1, Wm2, bm2, Wsp, bsp, u1v, u2v, nullptr);
    k_gate<<<8192, 256, 0, stream>>>(acat, Wg, bg, gatev);
    k_scan<<<64, 256, 0, stream>>>(role1, role2, fill, u1v, u2v, gatev, acat);
    // out = acat @ Wout^T + bout  (fp32 output)
    k_gemm_bt<<<dim3(256, 1), 256, 0, stream>>>(acat, 544, Woutb, nullptr, (float*)d_out, 128, bout, nullptr, 128, 544);
}

// Round 5
// 6170.469 us; speedup vs baseline: 2.1458x; 1.1970x over previous
//
#include <hip/hip_runtime.h>

typedef unsigned short u16;
typedef unsigned int u32;
typedef unsigned long long u64;
typedef __bf16 bf16x8 __attribute__((ext_vector_type(8)));
typedef float f32x4 __attribute__((ext_vector_type(4)));

__device__ __forceinline__ float bf2f(u16 u) { return __uint_as_float(((u32)u) << 16); }
__device__ __forceinline__ u16 f2bf(float f) {
    u32 u = __float_as_uint(f);
    u32 r = (u + 0x7FFFu + ((u >> 16) & 1u)) >> 16;
    return (u16)r;
}
__device__ __forceinline__ float sigm(float x) { return 1.0f / (1.0f + __expf(-x)); }
__device__ __forceinline__ float elu1(float x) { return x > 0.0f ? x + 1.0f : __expf(x); }

// LLC write (agent-scope relaxed atomic store = sc1, no L2 allocate).
__device__ __forceinline__ void llc_store2(u16* p, u16 a, u16 b) {
    u32 v = (u32)a | ((u32)b << 16);
    __hip_atomic_store((u32*)p, v, __ATOMIC_RELAXED, __HIP_MEMORY_SCOPE_AGENT);
}

// ---------------------------------------------------------------------------
// Batched fp32 -> bf16 cast: 8 segments in one launch.
// ---------------------------------------------------------------------------
struct Cvt8 { const float* s[8]; u16* d[8]; int off4[9]; };

__global__ __launch_bounds__(256) void k_f2b8(Cvt8 c)
{
    int i = blockIdx.x * 256 + threadIdx.x;
    if (i >= c.off4[8]) return;
    int k = 0;
#pragma unroll
    for (int q = 1; q < 8; q++) if (i >= c.off4[q]) k = q;
    int j = i - c.off4[k];
    float4 v = ((const float4*)c.s[k])[j];
    ushort4 o;
    o.x = f2bf(v.x); o.y = f2bf(v.y); o.z = f2bf(v.z); o.w = f2bf(v.w);
    ((ushort4*)c.d[k])[j] = o;
}

// ---------------------------------------------------------------------------
// Embedding: emb[row,:] = bf16(embed_W[tokens[row],:])  (row = t*64+b)
// ---------------------------------------------------------------------------
__global__ __launch_bounds__(256) void k_embed(const int* __restrict__ tok,
                                               const float* __restrict__ W,
                                               u16* __restrict__ out)
{
    int c = blockIdx.x * 256 + threadIdx.x;
    int row = c >> 5, cc = (c & 31) * 8;
    int t = tok[row];
    const float* src = W + (size_t)t * 256 + cc;
    u16 tmp[8];
#pragma unroll
    for (int k = 0; k < 8; k++) tmp[k] = f2bf(src[k]);
    *(uint4*)(out + (size_t)row * 256 + cc) = *(uint4*)tmp;
}

// ---------------------------------------------------------------------------
// GEMM:  C[M,N] = A[M,K](bf16, lda) * B[N,K]^T(bf16) + bias1 + bias2
// M = 32768, tile 128x128, BK=32, mfma 16x16x32 bf16. Out bf16 or fp32.
// ---------------------------------------------------------------------------
__global__ __launch_bounds__(256) void k_gemm_bt(
    const u16* __restrict__ A, int lda,
    const u16* __restrict__ B,
    u16* __restrict__ Cb, float* __restrict__ Cf, int ldc,
    const float* __restrict__ bias1, const float* __restrict__ bias2,
    int N, int K)
{
    __shared__ u16 As[128][40];
    __shared__ u16 Bs[128][40];
    const int tid = threadIdx.x;
    const int m0 = blockIdx.x * 128, n0 = blockIdx.y * 128;
    const int wave = tid >> 6, lane = tid & 63;
    const int wm = wave & 1, wn = wave >> 1;
    const int quad = lane >> 4, l16 = lane & 15;
    f32x4 acc[4][4] = {};
    for (int k0 = 0; k0 < K; k0 += 32) {
        __syncthreads();
#pragma unroll
        for (int i = 0; i < 2; i++) {
            int c = tid + i * 256, row = c >> 2, cc = (c & 3) * 8;
            *(uint4*)(&As[row][cc]) = *(const uint4*)(A + (size_t)(m0 + row) * lda + k0 + cc);
            uint4 d = {0, 0, 0, 0};
            if (n0 + row < N) d = *(const uint4*)(B + (size_t)(n0 + row) * K + k0 + cc);
            *(uint4*)(&Bs[row][cc]) = d;
        }
        __syncthreads();
        bf16x8 af[4], bfm[4];
#pragma unroll
        for (int x = 0; x < 4; x++) {
            af[x]  = *(const bf16x8*)(&As[wm * 64 + x * 16 + l16][quad * 8]);
            bfm[x] = *(const bf16x8*)(&Bs[wn * 64 + x * 16 + l16][quad * 8]);
        }
#pragma unroll
        for (int mi = 0; mi < 4; mi++)
#pragma unroll
            for (int ni = 0; ni < 4; ni++)
                acc[mi][ni] = __builtin_amdgcn_mfma_f32_16x16x32_bf16(af[mi], bfm[ni], acc[mi][ni], 0, 0, 0);
    }
#pragma unroll
    for (int ni = 0; ni < 4; ni++) {
        int col = n0 + wn * 64 + ni * 16 + l16;
        if (col < N) {
            float bv = 0.f;
            if (bias1) bv += bias1[col];
            if (bias2) bv += bias2[col];
#pragma unroll
            for (int mi = 0; mi < 4; mi++) {
                int r0 = m0 + wm * 64 + mi * 16 + quad * 4;
#pragma unroll
                for (int r = 0; r < 4; r++) {
                    float v = acc[mi][ni][r] + bv;
                    if (Cb) Cb[(size_t)(r0 + r) * ldc + col] = f2bf(v);
                    else    Cf[(size_t)(r0 + r) * ldc + col] = v;
                }
            }
        }
    }
}

// ---------------------------------------------------------------------------
// Fused 2-layer persistent LSTM, write-once h buffers + cached line reads.
// 128 blocks x 256 threads. Blocks 0..63: layer 0 (x=emb). 64..127: layer 1
// (x=h0seq), lagging one step. h written via sc1 stores to write-once
// addresses (h0seq / acat); consumers use NORMAL cached loads (first touch
// after the flag -> L2 miss -> fresh line from MALL, then shared per-XCD).
// Layer 0 at t needs f0[*] >= t. Layer 1 at t needs f0[*] >= t+1, f1[*] >= t.
// ---------------------------------------------------------------------------
__global__ __launch_bounds__(256) void k_lstm2(
    const u16* __restrict__ emb,    // [32768,256] bf16
    const u16* __restrict__ Wx0,    // [2048,256] bf16
    const u16* __restrict__ Wh0,    // [2048,512] bf16
    const u16* __restrict__ Wx1,    // [2048,512] bf16
    const u16* __restrict__ Wh1,    // [2048,512] bf16
    const float* __restrict__ bi0, const float* __restrict__ bh0,
    const float* __restrict__ bi1, const float* __restrict__ bh1,
    u16* __restrict__ h0seq,        // [512][64][512] bf16, write-once
    u16* __restrict__ acat,         // [32768,544]; cols 0..511 = h1, write-once
    int* __restrict__ flags)        // [2][64][16]
{
    __shared__ u16 Wx[32][520];
    __shared__ u16 Wh[32][520];
    __shared__ float zs[64][33];
    const int tid = threadIdx.x;
    const int layer = blockIdx.x >> 6;
    const int me = blockIdx.x & 63;
    const int jbase = me * 8;
    const int Kx = layer ? 512 : 256;
    const u16* Wxp = layer ? Wx1 : Wx0;
    const u16* Whp = layer ? Wh1 : Wh0;
    const float* bi = layer ? bi1 : bi0;
    const float* bh = layer ? bh1 : bh0;
    // Whh slice: 32 gate rows x 512
#pragma unroll
    for (int i = 0; i < 8; i++) {
        int c = tid + i * 256;
        int row = c >> 6, cc = (c & 63) * 8;
        int grow = (row >> 3) * 512 + jbase + (row & 7);
        *(uint4*)(&Wh[row][cc]) = *(const uint4*)(Whp + (size_t)grow * 512 + cc);
    }
    // Wih slice: 32 gate rows x Kx
    {
        int cpr = Kx >> 3;
        int iters = (32 * cpr) >> 8;
        for (int i = 0; i < iters; i++) {
            int c = tid + i * 256;
            int row = c / cpr, cc = (c % cpr) * 8;
            int grow = (row >> 3) * 512 + jbase + (row & 7);
            *(uint4*)(&Wx[row][cc]) = *(const uint4*)(Wxp + (size_t)grow * Kx + cc);
        }
    }
    const int wave = tid >> 6, lane = tid & 63;
    const int quad = lane >> 4, l16 = lane & 15;
    const int m = wave * 16 + l16;
    const int b = tid >> 2, jj = (tid & 3) * 2;   // this thread: batch b, cols jj,jj+1
    float bia0[4], bia1[4];
#pragma unroll
    for (int g = 0; g < 4; g++) {
        bia0[g] = bi[g * 512 + jbase + jj]     + bh[g * 512 + jbase + jj];
        bia1[g] = bi[g * 512 + jbase + jj + 1] + bh[g * 512 + jbase + jj + 1];
    }
    int* f0 = flags;
    int* f1 = flags + 1024;
    int* fown = layer ? f1 : f0;
    float c0 = 0.f, c1 = 0.f;
    __syncthreads();
    for (int t = 0; t < 512; t++) {
        f32x4 acc0 = {}, acc1 = {};
        // layer 0 x-part: independent of flags, compute before the wait
        if (!layer) {
            const u16* xrow = emb + ((size_t)t * 64 + m) * 256;
#pragma unroll
            for (int kc = 0; kc < 8; kc++) {
                bf16x8 a  = *(const bf16x8*)(xrow + kc * 32 + quad * 8);
                bf16x8 w0 = *(const bf16x8*)(&Wx[l16][kc * 32 + quad * 8]);
                bf16x8 w1 = *(const bf16x8*)(&Wx[16 + l16][kc * 32 + quad * 8]);
                acc0 = __builtin_amdgcn_mfma_f32_16x16x32_bf16(a, w0, acc0, 0, 0, 0);
                acc1 = __builtin_amdgcn_mfma_f32_16x16x32_bf16(a, w1, acc1, 0, 0, 0);
            }
        }
        // flag wait
        if (tid < 64) {
            if (layer) {
                int* p0 = f0 + tid * 16;
                int* p1 = f1 + tid * 16;
                for (;;) {
                    int a = __hip_atomic_load(p0, __ATOMIC_RELAXED, __HIP_MEMORY_SCOPE_AGENT);
                    int c = __hip_atomic_load(p1, __ATOMIC_RELAXED, __HIP_MEMORY_SCOPE_AGENT);
                    if (__all(a >= t + 1 && c >= t)) break;
                    __builtin_amdgcn_s_sleep(1);
                }
            } else if (t > 0) {
                int* p0 = f0 + tid * 16;
                for (;;) {
                    int a = __hip_atomic_load(p0, __ATOMIC_RELAXED, __HIP_MEMORY_SCOPE_AGENT);
                    if (__all(a >= t)) break;
                    __builtin_amdgcn_s_sleep(1);
                }
            }
        }
        __syncthreads();
        if (layer) {
            // x-part: h0seq[t] (cached loads; write-once lines, fresh via MALL)
            const u16* xrow = h0seq + ((size_t)t * 64 + m) * 512;
#pragma unroll
            for (int kc = 0; kc < 16; kc++) {
                bf16x8 a  = *(const bf16x8*)(xrow + kc * 32 + quad * 8);
                bf16x8 w0 = *(const bf16x8*)(&Wx[l16][kc * 32 + quad * 8]);
                bf16x8 w1 = *(const bf16x8*)(&Wx[16 + l16][kc * 32 + quad * 8]);
                acc0 = __builtin_amdgcn_mfma_f32_16x16x32_bf16(a, w0, acc0, 0, 0, 0);
                acc1 = __builtin_amdgcn_mfma_f32_16x16x32_bf16(a, w1, acc1, 0, 0, 0);
            }
            if (t > 0) {
                const u16* hrd = acat + ((size_t)(t - 1) * 64 + m) * 544;
#pragma unroll
                for (int kc = 0; kc < 16; kc++) {
                    bf16x8 a  = *(const bf16x8*)(hrd + kc * 32 + quad * 8);
                    bf16x8 w0 = *(const bf16x8*)(&Wh[l16][kc * 32 + quad * 8]);
                    bf16x8 w1 = *(const bf16x8*)(&Wh[16 + l16][kc * 32 + quad * 8]);
                    acc0 = __builtin_amdgcn_mfma_f32_16x16x32_bf16(a, w0, acc0, 0, 0, 0);
                    acc1 = __builtin_amdgcn_mfma_f32_16x16x32_bf16(a, w1, acc1, 0, 0, 0);
                }
            }
        } else if (t > 0) {
            const u16* hrd = h0seq + ((size_t)(t - 1) * 64 + m) * 512;
#pragma unroll
            for (int kc = 0; kc < 16; kc++) {
                bf16x8 a  = *(const bf16x8*)(hrd + kc * 32 + quad * 8);
                bf16x8 w0 = *(const bf16x8*)(&Wh[l16][kc * 32 + quad * 8]);
                bf16x8 w1 = *(const bf16x8*)(&Wh[16 + l16][kc * 32 + quad * 8]);
                acc0 = __builtin_amdgcn_mfma_f32_16x16x32_bf16(a, w0, acc0, 0, 0, 0);
                acc1 = __builtin_amdgcn_mfma_f32_16x16x32_bf16(a, w1, acc1, 0, 0, 0);
            }
        }
        {
            int zb = wave * 16 + quad * 4;
#pragma unroll
            for (int r = 0; r < 4; r++) { zs[zb + r][l16] = acc0[r]; zs[zb + r][16 + l16] = acc1[r]; }
        }
        __syncthreads();
        {
            float zi0 = zs[b][jj]      + bia0[0];
            float zf0 = zs[b][8 + jj]  + bia0[1];
            float zg0 = zs[b][16 + jj] + bia0[2];
            float zo0 = zs[b][24 + jj] + bia0[3];
            c0 = sigm(zf0) * c0 + sigm(zi0) * tanhf(zg0);
            float h0v = sigm(zo0) * tanhf(c0);
            float zi1 = zs[b][jj + 1]      + bia1[0];
            float zf1 = zs[b][8 + jj + 1]  + bia1[1];
            float zg1 = zs[b][16 + jj + 1] + bia1[2];
            float zo1 = zs[b][24 + jj + 1] + bia1[3];
            c1 = sigm(zf1) * c1 + sigm(zi1) * tanhf(zg1);
            float h1v = sigm(zo1) * tanhf(c1);
            u16 hb0 = f2bf(h0v), hb1 = f2bf(h1v);
            if (layer) llc_store2(acat  + ((size_t)t * 64 + b) * 544 + jbase + jj, hb0, hb1);
            else       llc_store2(h0seq + ((size_t)t * 64 + b) * 512 + jbase + jj, hb0, hb1);
        }
        __builtin_amdgcn_s_waitcnt(0);   // this wave's sc1 stores acked at LLC
        __syncthreads();                 // -> all waves' stores acked
        if (tid == 0)
            __hip_atomic_store(fown + me * 16, t + 1, __ATOMIC_RELAXED, __HIP_MEMORY_SCOPE_AGENT);
    }
}

// ---------------------------------------------------------------------------
// Slot attention (eval). 8 positions/block, 32 lanes per position.
// ---------------------------------------------------------------------------
template <int NSLOT>
__global__ __launch_bounds__(256) void k_slot(
    const u16* __restrict__ dec,    // [32768,192] bf16
    const u16* __restrict__ initp,  // [32768, NSLOT*32] bf16
    const float* __restrict__ Wq, const float* __restrict__ bq,
    const float* __restrict__ Wk, const float* __restrict__ bk,
    const float* __restrict__ Wv, const float* __restrict__ bv,
    const float* __restrict__ lng, const float* __restrict__ lnb,
    const float* __restrict__ Wm1, const float* __restrict__ bm1,
    const float* __restrict__ Wm2, const float* __restrict__ bm2,
    const float* __restrict__ Wsp, const float* __restrict__ bsp,
    float* __restrict__ o1, float* __restrict__ o2, float* __restrict__ o3)
{
    __shared__ float WqT[32][33], WkT[64][33], WvT[64][33], Wm1T[32][65], Wm2T[64][33], WspT[64][33];
    __shared__ float bq_s[32], bk_s[32], bv_s[32], bm1_s[64], bm2_s[32], bsp_s[32], g_s[32], be_s[32];
    __shared__ u16 xbuf[8][192];
    __shared__ float slots[8][3][32], initl[8][3][32], kk[8][3][32], vv[8][3][32], qq[8][3][32];
    __shared__ float att[8][3][4];
    __shared__ float ubuf[8][32];
    __shared__ float hid[8][64];
    const int tid = threadIdx.x;
    for (int i = tid; i < 1024; i += 256) { int o = i >> 5, c = i & 31; WqT[c][o] = Wq[o * 32 + c]; }
    for (int i = tid; i < 2048; i += 256) {
        int o6 = i >> 6, c6 = i & 63;
        WkT[c6][o6]  = Wk[o6 * 64 + c6];
        WvT[c6][o6]  = Wv[o6 * 64 + c6];
        Wm2T[c6][o6] = Wm2[o6 * 64 + c6];
        WspT[c6][o6] = Wsp[o6 * 64 + c6];
        int o5 = i >> 5, c5 = i & 31;
        Wm1T[c5][o5] = Wm1[o5 * 32 + c5];
    }
    if (tid < 32) {
        bq_s[tid] = bq[tid]; bk_s[tid] = bk[tid]; bv_s[tid] = bv[tid];
        bm2_s[tid] = bm2[tid]; bsp_s[tid] = bsp[tid];
        g_s[tid] = lng[tid]; be_s[tid] = lnb[tid];
    }
    if (tid < 64) bm1_s[tid] = bm1[tid];
    const int p = tid >> 5, l = tid & 31;
    const size_t row = (size_t)blockIdx.x * 8 + p;
    for (int i = l; i < 192; i += 32) xbuf[p][i] = dec[row * 192 + i];
    __syncthreads();

#pragma unroll
    for (int i = 0; i < 3; i++) {
        float aK = bk_s[l], aV = bv_s[l];
        for (int c = 0; c < 64; c++) {
            float x = bf2f(xbuf[p][i * 64 + c]);
            aK += x * WkT[c][l];
            aV += x * WvT[c][l];
        }
        kk[p][i][l] = elu1(aK);
        vv[p][i][l] = aV;
    }
#pragma unroll
    for (int j = 0; j < NSLOT; j++) {
        float iv = bf2f(initp[row * (NSLOT * 32) + j * 32 + l]);
        initl[p][j][l] = iv;
        slots[p][j][l] = iv;
    }
    __syncthreads();
    const float rs = 0.17677669529663687f;  // 32^-0.5
    for (int it = 0; it < 3; it++) {
#pragma unroll
        for (int j = 0; j < NSLOT; j++) {
            float a = bq_s[l];
            for (int c = 0; c < 32; c++) a += slots[p][j][c] * WqT[c][l];
            qq[p][j][l] = elu1((a + initl[p][j][l]) * rs);
        }
        __syncthreads();
        if (l < 3 * NSLOT) {
            int i = l / NSLOT, j = l % NSLOT;
            float s = 0.f;
            for (int c = 0; c < 32; c++) s += kk[p][i][c] * qq[p][j][c];
            att[p][i][j] = s;
        }
        __syncthreads();
        if (l < 3) {
            float mx = -1e30f;
            for (int j = 0; j < NSLOT; j++) mx = fmaxf(mx, att[p][l][j]);
            float sm = 0.f, ex[NSLOT];
            for (int j = 0; j < NSLOT; j++) { ex[j] = __expf(att[p][l][j] - mx); sm += ex[j]; }
            for (int j = 0; j < NSLOT; j++) att[p][l][j] = ex[j] / sm + 1e-8f;
        }
        __syncthreads();
        if (l < NSLOT) {
            float s = att[p][0][l] + att[p][1][l] + att[p][2][l];
            float inv = 1.0f / s;
            for (int i = 0; i < 3; i++) att[p][i][l] *= inv;
        }
        __syncthreads();
#pragma unroll
        for (int j = 0; j < NSLOT; j++) {
            float u = att[p][0][j] * vv[p][0][l] + att[p][1][j] * vv[p][1][l] + att[p][2][j] * vv[p][2][l];
            float mean = u;
            for (int mk = 1; mk < 32; mk <<= 1) mean += __shfl_xor(mean, mk, 32);
            mean *= (1.0f / 32.0f);
            float d = u - mean;
            float var = d * d;
            for (int mk = 1; mk < 32; mk <<= 1) var += __shfl_xor(var, mk, 32);
            var *= (1.0f / 32.0f);
            float y = d * rsqrtf(var + 1e-5f) * g_s[l] + be_s[l];
            ubuf[p][l] = y;
            __syncthreads();
#pragma unroll
            for (int oo = 0; oo < 2; oo++) {
                int o = l + oo * 32;
                float a = bm1_s[o];
                for (int c = 0; c < 32; c++) a += ubuf[p][c] * Wm1T[c][o];
                hid[p][o] = fmaxf(a, 0.f);
            }
            __syncthreads();
            float a2 = bm2_s[l];
            for (int c = 0; c < 64; c++) a2 += hid[p][c] * Wm2T[c][l];
            slots[p][j][l] += a2 * (1.0f / 32.0f);
            __syncthreads();
        }
    }
    float pj[NSLOT];
#pragma unroll
    for (int j = 0; j < NSLOT; j++) {
        float a = bsp_s[l];
        for (int c = 0; c < 32; c++) a += initl[p][j][c] * WspT[c][l];
        for (int c = 0; c < 32; c++) a += slots[p][j][c] * WspT[32 + c][l];
        pj[j] = a;
    }
    const float e = 1e-6f, me = (float)(1.0 - 2e-6);
    if (NSLOT == 3) {
        o1[row * 32 + l] = tanhf(me * pj[0] + e * pj[1] + e * pj[2]);
        o2[row * 32 + l] = tanhf(e * pj[0] + me * pj[1] + e * pj[2]);
        o3[row * 32 + l] = tanhf(e * pj[0] + e * pj[1] + me * pj[2]);
    } else {
        o1[row * 32 + l] = tanhf(me * pj[0] + e * pj[1]);
        o2[row * 32 + l] = tanhf(e * pj[0] + me * pj[1]);
    }
}

// ---------------------------------------------------------------------------
// gate[row] = sigmoid(h1[row,:512] . Wg + bg + 1). One wave per row.
// ---------------------------------------------------------------------------
__global__ __launch_bounds__(256) void k_gate(
    const u16* __restrict__ acat, const float* __restrict__ Wg,
    const float* __restrict__ bg, float* __restrict__ gate)
{
    const int row = blockIdx.x * 4 + (threadIdx.x >> 6);
    const int lane = threadIdx.x & 63;
    const u16* h = acat + (size_t)row * 544;
    float s = 0.f;
    for (int c = lane; c < 512; c += 64) s += bf2f(h[c]) * Wg[c];
    for (int mk = 1; mk < 64; mk <<= 1) s += __shfl_xor(s, mk, 64);
    if (lane == 0) gate[row] = sigm(s + bg[0] + 1.0f);
}

// ---------------------------------------------------------------------------
// Memory scan. One block per batch b; mem[32][32][32] fp32 in registers.
// Inputs for step t+1 prefetched into a register during step t's compute.
// ---------------------------------------------------------------------------
__global__ __launch_bounds__(256) void k_scan(
    const float* __restrict__ r1, const float* __restrict__ r2,
    const float* __restrict__ fi, const float* __restrict__ uu1,
    const float* __restrict__ uu2, const float* __restrict__ gg,
    u16* __restrict__ acat)
{
    const int b = blockIdx.x, tid = threadIdx.x;
    const int f = tid & 31, rg = tid >> 5;
    float m[4][32];
#pragma unroll
    for (int x = 0; x < 4; x++)
        for (int y = 0; y < 32; y++) m[x][y] = 0.f;
    __shared__ float r1s[32], r2s[32], fis[32], u1s[32], u2s[32];
    __shared__ float red[8][32];
    __shared__ float wred[4];
    __shared__ float gsh;
    float pre = 0.f;
    {
        size_t base = (size_t)b * 32;
        if (tid < 32) pre = r1[base + tid];
        else if (tid < 64) pre = r2[base + tid - 32];
        else if (tid < 96) pre = fi[base + tid - 64];
        else if (tid < 128) pre = uu1[base + tid - 96];
        else if (tid < 160) pre = uu2[base + tid - 128];
        else if (tid == 160) pre = gg[b];
    }
    for (int t = 0; t < 512; t++) {
        if (tid < 32) r1s[tid] = pre;
        else if (tid < 64) r2s[tid - 32] = pre;
        else if (tid < 96) fis[tid - 64] = pre;
        else if (tid < 128) u1s[tid - 96] = pre;
        else if (tid < 160) u2s[tid - 128] = pre;
        else if (tid == 160) gsh = pre;
        __syncthreads();
        if (t + 1 < 512) {
            size_t base = ((size_t)(t + 1) * 64 + b) * 32;
            if (tid < 32) pre = r1[base + tid];
            else if (tid < 64) pre = r2[base + tid - 32];
            else if (tid < 96) pre = fi[base + tid - 64];
            else if (tid < 128) pre = uu1[base + tid - 96];
            else if (tid < 160) pre = uu2[base + tid - 128];
            else if (tid == 160) pre = gg[(t + 1) * 64 + b];
        }
        float p = 0.f;
#pragma unroll
        for (int rl = 0; rl < 4; rl++) {
            float s = 0.f;
            for (int ti = 0; ti < 32; ti++) s += r2s[ti] * m[rl][ti];
            p += r1s[rg * 4 + rl] * s;
        }
        red[rg][f] = p;
        __syncthreads();
        float prev = 0.f;
#pragma unroll
        for (int g = 0; g < 8; g++) prev += red[g][f];
        float curo = gsh * (fis[f] - prev) * (1.0f / 32.0f);
        float nsq = 0.f;
#pragma unroll
        for (int rl = 0; rl < 4; rl++) {
            float a = r1s[rg * 4 + rl] * curo;
            for (int ti = 0; ti < 32; ti++) {
                m[rl][ti] += a * r2s[ti];
                nsq += m[rl][ti] * m[rl][ti];
            }
        }
        for (int mk = 1; mk < 64; mk <<= 1) nsq += __shfl_xor(nsq, mk, 64);
        __syncthreads();
        if ((tid & 63) == 0) wred[tid >> 6] = nsq;
        __syncthreads();
        float nrm = sqrtf(wred[0] + wred[1] + wred[2] + wred[3]);
        float sc = nrm > 1.0f ? 1.0f / nrm : 1.0f;   // relu(nrm-1)+1 == max(nrm,1)
        float rp = 0.f;
#pragma unroll
        for (int rl = 0; rl < 4; rl++) {
            float s = 0.f;
            for (int ti = 0; ti < 32; ti++) {
                m[rl][ti] *= sc;
                s += m[rl][ti] * u2s[ti];
            }
            rp += u1s[rg * 4 + rl] * s;
        }
        red[rg][f] = rp;
        __syncthreads();
        float rv = 0.f;
#pragma unroll
        for (int g = 0; g < 8; g++) rv += red[g][f];
        float mean = rv;
        for (int mk = 1; mk < 32; mk <<= 1) mean += __shfl_xor(mean, mk, 32);
        mean *= (1.0f / 32.0f);
        float d = rv - mean;
        float var = d * d;
        for (int mk = 1; mk < 32; mk <<= 1) var += __shfl_xor(var, mk, 32);
        var *= (1.0f / 32.0f);
        if (tid < 32) {
            float y = d * rsqrtf(var + 1e-5f);
            acat[((size_t)t * 64 + b) * 544 + 512 + f] = f2bf(y);
        }
        __syncthreads();
    }
}

// ---------------------------------------------------------------------------
extern "C" void kernel_launch(void* const* d_in, const int* in_sizes, int n_in,
                              void* d_out, int out_size, void* d_ws, size_t ws_size,
                              hipStream_t stream)
{
    (void)in_sizes; (void)n_in; (void)out_size; (void)ws_size;
    const int*   tokens = (const int*)d_in[0];
    const float* embW  = (const float*)d_in[1];
    const float* Wih0  = (const float*)d_in[2];
    const float* Whh0  = (const float*)d_in[3];
    const float* bih0  = (const float*)d_in[4];
    const float* bhh0  = (const float*)d_in[5];
    const float* Wih1  = (const float*)d_in[6];
    const float* Whh1  = (const float*)d_in[7];
    const float* bih1  = (const float*)d_in[8];
    const float* bhh1  = (const float*)d_in[9];
    const float* Wpi   = (const float*)d_in[10];
    const float* bpi   = (const float*)d_in[11];
    const float* Wq    = (const float*)d_in[12];
    const float* bq    = (const float*)d_in[13];
    const float* Wk    = (const float*)d_in[14];
    const float* bk    = (const float*)d_in[15];
    const float* Wv    = (const float*)d_in[16];
    const float* bv    = (const float*)d_in[17];
    const float* lng   = (const float*)d_in[18];
    const float* lnb   = (const float*)d_in[19];
    const float* Wm1   = (const float*)d_in[20];
    const float* bm1   = (const float*)d_in[21];
    const float* Wm2   = (const float*)d_in[22];
    const float* bm2   = (const float*)d_in[23];
    const float* Wbind = (const float*)d_in[24];
    const float* bbind = (const float*)d_in[25];
    const float* Wreas = (const float*)d_in[26];
    const float* breas = (const float*)d_in[27];
    const float* Wsp   = (const float*)d_in[28];
    const float* bsp   = (const float*)d_in[29];
    const float* Wg    = (const float*)d_in[30];
    const float* bg    = (const float*)d_in[31];
    const float* Wout  = (const float*)d_in[32];
    const float* bout  = (const float*)d_in[33];

    // workspace (~138 MB total)
    char* ws = (char*)d_ws;
    size_t off = 0;
    auto alloc = [&](size_t bytes) { size_t o = off; off += (bytes + 255) & ~(size_t)255; return o; };
    int*  flags  = (int*)(ws + alloc(2 * 64 * 16 * 4));
    u16*  emb    = (u16*)(ws + alloc(32768ull * 256 * 2));
    u16*  dec    = (u16*)(ws + alloc(32768ull * 192 * 2));
    u16*  initb  = (u16*)(ws + alloc(32768ull * 96 * 2));
    u16*  initr  = (u16*)(ws + alloc(32768ull * 64 * 2));
    u16*  acat   = (u16*)(ws + alloc(32768ull * 544 * 2));    // [h1(512) | reads(32)]
    u16*  h0seq  = (u16*)(ws + alloc(512ull * 64 * 512 * 2)); // write-once h0
    float* role1 = (float*)(ws + alloc(32768ull * 32 * 4));
    float* role2 = (float*)(ws + alloc(32768ull * 32 * 4));
    float* fill  = (float*)(ws + alloc(32768ull * 32 * 4));
    float* u1v   = (float*)(ws + alloc(32768ull * 32 * 4));
    float* u2v   = (float*)(ws + alloc(32768ull * 32 * 4));
    float* gatev = (float*)(ws + alloc(32768ull * 4));
    u16* Wx0b  = (u16*)(ws + alloc(2048ull * 256 * 2));
    u16* Wh0b  = (u16*)(ws + alloc(2048ull * 512 * 2));
    u16* Wx1b  = (u16*)(ws + alloc(2048ull * 512 * 2));
    u16* Wh1b  = (u16*)(ws + alloc(2048ull * 512 * 2));
    u16* Wpib  = (u16*)(ws + alloc(192ull * 256 * 2));
    u16* Wbindb = (u16*)(ws + alloc(96ull * 192 * 2));
    u16* Wreasb = (u16*)(ws + alloc(64ull * 192 * 2));
    u16* Woutb  = (u16*)(ws + alloc(128ull * 544 * 2));

    hipMemsetAsync(flags, 0, 2 * 64 * 16 * 4, stream);
    // one batched weight-cast launch
    {
        Cvt8 c;
        const float* s[8] = {Wih0, Whh0, Wih1, Whh1, Wpi, Wbind, Wreas, Wout};
        u16* d[8] = {Wx0b, Wh0b, Wx1b, Wh1b, Wpib, Wbindb, Wreasb, Woutb};
        int n[8] = {2048 * 256, 2048 * 512, 2048 * 512, 2048 * 512,
                    192 * 256, 96 * 192, 64 * 192, 128 * 544};
        int acc = 0;
        for (int k = 0; k < 8; k++) { c.s[k] = s[k]; c.d[k] = d[k]; c.off4[k] = acc; acc += n[k] / 4; }
        c.off4[8] = acc;
        k_f2b8<<<(acc + 255) / 256, 256, 0, stream>>>(c);
    }

    k_embed<<<4096, 256, 0, stream>>>(tokens, embW, emb);
    // dec_in = emb @ Wpi^T + bpi
    k_gemm_bt<<<dim3(256, 2), 256, 0, stream>>>(emb, 256, Wpib, dec, nullptr, 192, bpi, nullptr, 192, 256);
    // slot inits
    k_gemm_bt<<<dim3(256, 1), 256, 0, stream>>>(dec, 192, Wbindb, initb, nullptr, 96, bbind, nullptr, 96, 192);
    k_gemm_bt<<<dim3(256, 1), 256, 0, stream>>>(dec, 192, Wreasb, initr, nullptr, 64, breas, nullptr, 64, 192);
    // fused 2-layer LSTM (h1 -> acat cols 0..511)
    k_lstm2<<<128, 256, 0, stream>>>(emb, Wx0b, Wh0b, Wx1b, Wh1b,
                                     bih0, bhh0, bih1, bhh1,
                                     h0seq, acat, flags);
    // slot attention
    k_slot<3><<<4096, 256, 0, stream>>>(dec, initb, Wq, bq, Wk, bk, Wv, bv, lng, lnb,
                                        Wm1, bm1, Wm2, bm2, Wsp, bsp, role1, role2, fill);
    k_slot<2><<<4096, 256, 0, stream>>>(dec, initr, Wq, bq, Wk, bk, Wv, bv, lng, lnb,
                                        Wm1, bm1, Wm2, bm2, Wsp, bsp, u1v, u2v, nullptr);
    k_gate<<<8192, 256, 0, stream>>>(acat, Wg, bg, gatev);
    k_scan<<<64, 256, 0, stream>>>(role1, role2, fill, u1v, u2v, gatev, acat);
    // out = acat @ Wout^T + bout  (fp32 output)
    k_gemm_bt<<<dim3(256, 1), 256, 0, stream>>>(acat, 544, Woutb, nullptr, (float*)d_out, 128, bout, nullptr, 128, 544);
}

// Round 7
// 4578.990 us; speedup vs baseline: 2.8917x; 1.3476x over previous
//
#include <hip/hip_runtime.h>

typedef unsigned short u16;
typedef unsigned int u32;
typedef unsigned long long u64;
typedef __bf16 bf16x8 __attribute__((ext_vector_type(8)));
typedef float f32x4 __attribute__((ext_vector_type(4)));

__device__ __forceinline__ float bf2f(u16 u) { return __uint_as_float(((u32)u) << 16); }
__device__ __forceinline__ u16 f2bf(float f) {
    u32 u = __float_as_uint(f);
    u32 r = (u + 0x7FFFu + ((u >> 16) & 1u)) >> 16;
    return (u16)r;
}
__device__ __forceinline__ float sigm(float x) { return 1.0f / (1.0f + __expf(-x)); }
__device__ __forceinline__ float elu1(float x) { return x > 0.0f ? x + 1.0f : __expf(x); }

// agent-scope (LLC) atomics — the HW-validated cross-XCD path (R5)
__device__ __forceinline__ int ag_load(const int* p) {
    return __hip_atomic_load(p, __ATOMIC_RELAXED, __HIP_MEMORY_SCOPE_AGENT);
}
__device__ __forceinline__ void ag_store(int* p, int v) {
    __hip_atomic_store(p, v, __ATOMIC_RELAXED, __HIP_MEMORY_SCOPE_AGENT);
}
__device__ __forceinline__ void llc_store2(u16* p, u16 a, u16 b) {
    u32 v = (u32)a | ((u32)b << 16);
    __hip_atomic_store((u32*)p, v, __ATOMIC_RELAXED, __HIP_MEMORY_SCOPE_AGENT);
}
__device__ __forceinline__ void llc_store_u16(u16* p, u16 v) {
    __hip_atomic_store(p, v, __ATOMIC_RELAXED, __HIP_MEMORY_SCOPE_AGENT);
}

// ---------------------------------------------------------------------------
// Batched fp32 -> bf16 cast: 8 segments in one launch.
// ---------------------------------------------------------------------------
struct Cvt8 { const float* s[8]; u16* d[8]; int off4[9]; };

__global__ __launch_bounds__(256) void k_f2b8(Cvt8 c)
{
    int i = blockIdx.x * 256 + threadIdx.x;
    if (i >= c.off4[8]) return;
    int k = 0;
#pragma unroll
    for (int q = 1; q < 8; q++) if (i >= c.off4[q]) k = q;
    int j = i - c.off4[k];
    float4 v = ((const float4*)c.s[k])[j];
    ushort4 o;
    o.x = f2bf(v.x); o.y = f2bf(v.y); o.z = f2bf(v.z); o.w = f2bf(v.w);
    ((ushort4*)c.d[k])[j] = o;
}

// ---------------------------------------------------------------------------
__global__ __launch_bounds__(256) void k_embed(const int* __restrict__ tok,
                                               const float* __restrict__ W,
                                               u16* __restrict__ out)
{
    int c = blockIdx.x * 256 + threadIdx.x;
    int row = c >> 5, cc = (c & 31) * 8;
    int t = tok[row];
    const float* src = W + (size_t)t * 256 + cc;
    u16 tmp[8];
#pragma unroll
    for (int k = 0; k < 8; k++) tmp[k] = f2bf(src[k]);
    *(uint4*)(out + (size_t)row * 256 + cc) = *(uint4*)tmp;
}

// ---------------------------------------------------------------------------
// GEMM:  C[M,N] = A[M,K](bf16, lda) * B[N,K]^T(bf16) + bias. 128x128 tile.
// ---------------------------------------------------------------------------
__global__ __launch_bounds__(256) void k_gemm_bt(
    const u16* __restrict__ A, int lda,
    const u16* __restrict__ B,
    u16* __restrict__ Cb, float* __restrict__ Cf, int ldc,
    const float* __restrict__ bias1, const float* __restrict__ bias2,
    int N, int K)
{
    __shared__ u16 As[128][40];
    __shared__ u16 Bs[128][40];
    const int tid = threadIdx.x;
    const int m0 = blockIdx.x * 128, n0 = blockIdx.y * 128;
    const int wave = tid >> 6, lane = tid & 63;
    const int wm = wave & 1, wn = wave >> 1;
    const int quad = lane >> 4, l16 = lane & 15;
    f32x4 acc[4][4] = {};
    for (int k0 = 0; k0 < K; k0 += 32) {
        __syncthreads();
#pragma unroll
        for (int i = 0; i < 2; i++) {
            int c = tid + i * 256, row = c >> 2, cc = (c & 3) * 8;
            *(uint4*)(&As[row][cc]) = *(const uint4*)(A + (size_t)(m0 + row) * lda + k0 + cc);
            uint4 d = {0, 0, 0, 0};
            if (n0 + row < N) d = *(const uint4*)(B + (size_t)(n0 + row) * K + k0 + cc);
            *(uint4*)(&Bs[row][cc]) = d;
        }
        __syncthreads();
        bf16x8 af[4], bfm[4];
#pragma unroll
        for (int x = 0; x < 4; x++) {
            af[x]  = *(const bf16x8*)(&As[wm * 64 + x * 16 + l16][quad * 8]);
            bfm[x] = *(const bf16x8*)(&Bs[wn * 64 + x * 16 + l16][quad * 8]);
        }
#pragma unroll
        for (int mi = 0; mi < 4; mi++)
#pragma unroll
            for (int ni = 0; ni < 4; ni++)
                acc[mi][ni] = __builtin_amdgcn_mfma_f32_16x16x32_bf16(af[mi], bfm[ni], acc[mi][ni], 0, 0, 0);
    }
#pragma unroll
    for (int ni = 0; ni < 4; ni++) {
        int col = n0 + wn * 64 + ni * 16 + l16;
        if (col < N) {
            float bv = 0.f;
            if (bias1) bv += bias1[col];
            if (bias2) bv += bias2[col];
#pragma unroll
            for (int mi = 0; mi < 4; mi++) {
                int r0 = m0 + wm * 64 + mi * 16 + quad * 4;
#pragma unroll
                for (int r = 0; r < 4; r++) {
                    float v = acc[mi][ni][r] + bv;
                    if (Cb) Cb[(size_t)(r0 + r) * ldc + col] = f2bf(v);
                    else    Cf[(size_t)(r0 + r) * ldc + col] = v;
                }
            }
        }
    }
}

// ---------------------------------------------------------------------------
// Slot attention (standalone, R5-proven). 8 positions/block.
// ---------------------------------------------------------------------------
template <int NSLOT>
__global__ __launch_bounds__(256) void k_slot(
    const u16* __restrict__ dec, const u16* __restrict__ initp,
    const float* __restrict__ Wq, const float* __restrict__ bq,
    const float* __restrict__ Wk, const float* __restrict__ bk,
    const float* __restrict__ Wv, const float* __restrict__ bv,
    const float* __restrict__ lng, const float* __restrict__ lnb,
    const float* __restrict__ Wm1, const float* __restrict__ bm1,
    const float* __restrict__ Wm2, const float* __restrict__ bm2,
    const float* __restrict__ Wsp, const float* __restrict__ bsp,
    float* __restrict__ o1, float* __restrict__ o2, float* __restrict__ o3)
{
    __shared__ float WqT[32][33], WkT[64][33], WvT[64][33], Wm1T[32][65], Wm2T[64][33], WspT[64][33];
    __shared__ float bq_s[32], bk_s[32], bv_s[32], bm1_s[64], bm2_s[32], bsp_s[32], g_s[32], be_s[32];
    __shared__ u16 xbuf[8][192];
    __shared__ float slots[8][3][32], initl[8][3][32], kk[8][3][32], vv[8][3][32], qq[8][3][32];
    __shared__ float att[8][3][4];
    __shared__ float ubuf[8][32];
    __shared__ float hid[8][64];
    const int tid = threadIdx.x;
    for (int i = tid; i < 1024; i += 256) { int o = i >> 5, c = i & 31; WqT[c][o] = Wq[o * 32 + c]; }
    for (int i = tid; i < 2048; i += 256) {
        int o6 = i >> 6, c6 = i & 63;
        WkT[c6][o6]  = Wk[o6 * 64 + c6];
        WvT[c6][o6]  = Wv[o6 * 64 + c6];
        Wm2T[c6][o6] = Wm2[o6 * 64 + c6];
        WspT[c6][o6] = Wsp[o6 * 64 + c6];
        int o5 = i >> 5, c5 = i & 31;
        Wm1T[c5][o5] = Wm1[o5 * 32 + c5];
    }
    if (tid < 32) {
        bq_s[tid] = bq[tid]; bk_s[tid] = bk[tid]; bv_s[tid] = bv[tid];
        bm2_s[tid] = bm2[tid]; bsp_s[tid] = bsp[tid];
        g_s[tid] = lng[tid]; be_s[tid] = lnb[tid];
    }
    if (tid < 64) bm1_s[tid] = bm1[tid];
    const int p = tid >> 5, l = tid & 31;
    const size_t row = (size_t)blockIdx.x * 8 + p;
    for (int i = l; i < 192; i += 32) xbuf[p][i] = dec[row * 192 + i];
    __syncthreads();
#pragma unroll
    for (int i = 0; i < 3; i++) {
        float aK = bk_s[l], aV = bv_s[l];
        for (int c = 0; c < 64; c++) {
            float x = bf2f(xbuf[p][i * 64 + c]);
            aK += x * WkT[c][l];
            aV += x * WvT[c][l];
        }
        kk[p][i][l] = elu1(aK);
        vv[p][i][l] = aV;
    }
#pragma unroll
    for (int j = 0; j < NSLOT; j++) {
        float iv = bf2f(initp[row * (NSLOT * 32) + j * 32 + l]);
        initl[p][j][l] = iv;
        slots[p][j][l] = iv;
    }
    __syncthreads();
    const float rs = 0.17677669529663687f;
    for (int it = 0; it < 3; it++) {
#pragma unroll
        for (int j = 0; j < NSLOT; j++) {
            float a = bq_s[l];
            for (int c = 0; c < 32; c++) a += slots[p][j][c] * WqT[c][l];
            qq[p][j][l] = elu1((a + initl[p][j][l]) * rs);
        }
        __syncthreads();
        if (l < 3 * NSLOT) {
            int i = l / NSLOT, j = l % NSLOT;
            float s = 0.f;
            for (int c = 0; c < 32; c++) s += kk[p][i][c] * qq[p][j][c];
            att[p][i][j] = s;
        }
        __syncthreads();
        if (l < 3) {
            float mx = -1e30f;
            for (int j = 0; j < NSLOT; j++) mx = fmaxf(mx, att[p][l][j]);
            float sm = 0.f, ex[NSLOT];
            for (int j = 0; j < NSLOT; j++) { ex[j] = __expf(att[p][l][j] - mx); sm += ex[j]; }
            for (int j = 0; j < NSLOT; j++) att[p][l][j] = ex[j] / sm + 1e-8f;
        }
        __syncthreads();
        if (l < NSLOT) {
            float s = att[p][0][l] + att[p][1][l] + att[p][2][l];
            float inv = 1.0f / s;
            for (int i = 0; i < 3; i++) att[p][i][l] *= inv;
        }
        __syncthreads();
#pragma unroll
        for (int j = 0; j < NSLOT; j++) {
            float u = att[p][0][j] * vv[p][0][l] + att[p][1][j] * vv[p][1][l] + att[p][2][j] * vv[p][2][l];
            float mean = u;
            for (int mk = 1; mk < 32; mk <<= 1) mean += __shfl_xor(mean, mk, 32);
            mean *= (1.0f / 32.0f);
            float d = u - mean;
            float var = d * d;
            for (int mk = 1; mk < 32; mk <<= 1) var += __shfl_xor(var, mk, 32);
            var *= (1.0f / 32.0f);
            float y = d * rsqrtf(var + 1e-5f) * g_s[l] + be_s[l];
            ubuf[p][l] = y;
            __syncthreads();
#pragma unroll
            for (int oo = 0; oo < 2; oo++) {
                int o = l + oo * 32;
                float a = bm1_s[o];
                for (int c = 0; c < 32; c++) a += ubuf[p][c] * Wm1T[c][o];
                hid[p][o] = fmaxf(a, 0.f);
            }
            __syncthreads();
            float a2 = bm2_s[l];
            for (int c = 0; c < 64; c++) a2 += hid[p][c] * Wm2T[c][l];
            slots[p][j][l] += a2 * (1.0f / 32.0f);
            __syncthreads();
        }
    }
    float pj[NSLOT];
#pragma unroll
    for (int j = 0; j < NSLOT; j++) {
        float a = bsp_s[l];
        for (int c = 0; c < 32; c++) a += initl[p][j][c] * WspT[c][l];
        for (int c = 0; c < 32; c++) a += slots[p][j][c] * WspT[32 + c][l];
        pj[j] = a;
    }
    const float e = 1e-6f, me = (float)(1.0 - 2e-6);
    if (NSLOT == 3) {
        o1[row * 32 + l] = tanhf(me * pj[0] + e * pj[1] + e * pj[2]);
        o2[row * 32 + l] = tanhf(e * pj[0] + me * pj[1] + e * pj[2]);
        o3[row * 32 + l] = tanhf(e * pj[0] + e * pj[1] + me * pj[2]);
    } else {
        o1[row * 32 + l] = tanhf(me * pj[0] + e * pj[1]);
        o2[row * 32 + l] = tanhf(e * pj[0] + me * pj[1]);
    }
}

// ---------------------------------------------------------------------------
// Mega kernel: 192 blocks.
//   0..63   : LSTM layer 0 (R5 logic verbatim, LDS stride 528)
//   64..127 : LSTM layer 1 (lagging one step)
//   128..191: memory-scan for batch b = blk-128, TRAILING layer 1 via f1
//             flags; gate computed inline from acat h1.
// Sync = R5-proven: agent-scope flags + write-once payloads (sc1 stores,
// normal cached first-touch loads). No XCD games.
// ---------------------------------------------------------------------------
__global__ __launch_bounds__(256) void k_mega(
    const u16* __restrict__ emb,
    const u16* __restrict__ Wx0, const u16* __restrict__ Wh0,
    const u16* __restrict__ Wx1, const u16* __restrict__ Wh1,
    const float* __restrict__ bi0, const float* __restrict__ bh0,
    const float* __restrict__ bi1, const float* __restrict__ bh1,
    u16* __restrict__ h0seq,        // [512][64][512] write-once
    u16* __restrict__ acat,         // [32768][544]; cols 0..511 h1 (write-once), 512.. scan out
    int* __restrict__ flags,        // f0 @0, f1 @1024 (stride-16 ints)
    const float* __restrict__ r1, const float* __restrict__ r2,
    const float* __restrict__ fi, const float* __restrict__ uu1,
    const float* __restrict__ uu2,
    const float* __restrict__ Wg, const float* __restrict__ bg)
{
    const int tid = threadIdx.x;
    const int blk = blockIdx.x;
    int* f0 = flags;
    int* f1 = flags + 1024;

    if (blk < 128) {
        // ======================= LSTM (R5 verbatim + stride 528) ===========
        __shared__ u16 Wx[32][528];
        __shared__ u16 Wh[32][528];
        __shared__ float zs[64][33];
        const int layer = blk >> 6;
        const int me = blk & 63;
        const int jbase = me * 8;
        const int Kx = layer ? 512 : 256;
        const u16* Wxp = layer ? Wx1 : Wx0;
        const u16* Whp = layer ? Wh1 : Wh0;
        const float* bi = layer ? bi1 : bi0;
        const float* bh = layer ? bh1 : bh0;
#pragma unroll
        for (int i = 0; i < 8; i++) {
            int c = tid + i * 256;
            int row = c >> 6, cc = (c & 63) * 8;
            int grow = (row >> 3) * 512 + jbase + (row & 7);
            *(uint4*)(&Wh[row][cc]) = *(const uint4*)(Whp + (size_t)grow * 512 + cc);
        }
        {
            int cpr = Kx >> 3;
            int iters = (32 * cpr) >> 8;
            for (int i = 0; i < iters; i++) {
                int c = tid + i * 256;
                int row = c / cpr, cc = (c % cpr) * 8;
                int grow = (row >> 3) * 512 + jbase + (row & 7);
                *(uint4*)(&Wx[row][cc]) = *(const uint4*)(Wxp + (size_t)grow * Kx + cc);
            }
        }
        const int wave = tid >> 6, lane = tid & 63;
        const int quad = lane >> 4, l16 = lane & 15;
        const int m = wave * 16 + l16;
        const int b = tid >> 2, jj = (tid & 3) * 2;
        float bia0[4], bia1[4];
#pragma unroll
        for (int g = 0; g < 4; g++) {
            bia0[g] = bi[g * 512 + jbase + jj]     + bh[g * 512 + jbase + jj];
            bia1[g] = bi[g * 512 + jbase + jj + 1] + bh[g * 512 + jbase + jj + 1];
        }
        int* fown = layer ? f1 : f0;
        float c0 = 0.f, c1 = 0.f;
        __syncthreads();
        for (int t = 0; t < 512; t++) {
            f32x4 acc0 = {}, acc1 = {};
            if (!layer) {   // x-part before the wait (independent of flags)
                const u16* xrow = emb + ((size_t)t * 64 + m) * 256;
#pragma unroll
                for (int kc = 0; kc < 8; kc++) {
                    bf16x8 a  = *(const bf16x8*)(xrow + kc * 32 + quad * 8);
                    bf16x8 w0 = *(const bf16x8*)(&Wx[l16][kc * 32 + quad * 8]);
                    bf16x8 w1 = *(const bf16x8*)(&Wx[16 + l16][kc * 32 + quad * 8]);
                    acc0 = __builtin_amdgcn_mfma_f32_16x16x32_bf16(a, w0, acc0, 0, 0, 0);
                    acc1 = __builtin_amdgcn_mfma_f32_16x16x32_bf16(a, w1, acc1, 0, 0, 0);
                }
            }
            if (tid < 64) {
                if (layer) {
                    int* p0 = f0 + tid * 16;
                    int* p1 = f1 + tid * 16;
                    int it = 0;
                    for (;;) {
                        int a = ag_load(p0);
                        int c = ag_load(p1);
                        if (__all(a >= t + 1 && c >= t)) break;
                        if (++it > 3000000) break;
                        __builtin_amdgcn_s_sleep(1);
                    }
                } else if (t > 0) {
                    int* p0 = f0 + tid * 16;
                    int it = 0;
                    for (;;) {
                        int a = ag_load(p0);
                        if (__all(a >= t)) break;
                        if (++it > 3000000) break;
                        __builtin_amdgcn_s_sleep(1);
                    }
                }
            }
            __syncthreads();
            if (layer) {
                const u16* xrow = h0seq + ((size_t)t * 64 + m) * 512;
#pragma unroll
                for (int kc = 0; kc < 16; kc++) {
                    bf16x8 a  = *(const bf16x8*)(xrow + kc * 32 + quad * 8);
                    bf16x8 w0 = *(const bf16x8*)(&Wx[l16][kc * 32 + quad * 8]);
                    bf16x8 w1 = *(const bf16x8*)(&Wx[16 + l16][kc * 32 + quad * 8]);
                    acc0 = __builtin_amdgcn_mfma_f32_16x16x32_bf16(a, w0, acc0, 0, 0, 0);
                    acc1 = __builtin_amdgcn_mfma_f32_16x16x32_bf16(a, w1, acc1, 0, 0, 0);
                }
                if (t > 0) {
                    const u16* hrd = acat + ((size_t)(t - 1) * 64 + m) * 544;
#pragma unroll
                    for (int kc = 0; kc < 16; kc++) {
                        bf16x8 a  = *(const bf16x8*)(hrd + kc * 32 + quad * 8);
                        bf16x8 w0 = *(const bf16x8*)(&Wh[l16][kc * 32 + quad * 8]);
                        bf16x8 w1 = *(const bf16x8*)(&Wh[16 + l16][kc * 32 + quad * 8]);
                        acc0 = __builtin_amdgcn_mfma_f32_16x16x32_bf16(a, w0, acc0, 0, 0, 0);
                        acc1 = __builtin_amdgcn_mfma_f32_16x16x32_bf16(a, w1, acc1, 0, 0, 0);
                    }
                }
            } else if (t > 0) {
                const u16* hrd = h0seq + ((size_t)(t - 1) * 64 + m) * 512;
#pragma unroll
                for (int kc = 0; kc < 16; kc++) {
                    bf16x8 a  = *(const bf16x8*)(hrd + kc * 32 + quad * 8);
                    bf16x8 w0 = *(const bf16x8*)(&Wh[l16][kc * 32 + quad * 8]);
                    bf16x8 w1 = *(const bf16x8*)(&Wh[16 + l16][kc * 32 + quad * 8]);
                    acc0 = __builtin_amdgcn_mfma_f32_16x16x32_bf16(a, w0, acc0, 0, 0, 0);
                    acc1 = __builtin_amdgcn_mfma_f32_16x16x32_bf16(a, w1, acc1, 0, 0, 0);
                }
            }
            {
                int zb = wave * 16 + quad * 4;
#pragma unroll
                for (int r = 0; r < 4; r++) { zs[zb + r][l16] = acc0[r]; zs[zb + r][16 + l16] = acc1[r]; }
            }
            __syncthreads();
            {
                float zi0 = zs[b][jj]      + bia0[0];
                float zf0 = zs[b][8 + jj]  + bia0[1];
                float zg0 = zs[b][16 + jj] + bia0[2];
                float zo0 = zs[b][24 + jj] + bia0[3];
                c0 = sigm(zf0) * c0 + sigm(zi0) * tanhf(zg0);
                float h0v = sigm(zo0) * tanhf(c0);
                float zi1 = zs[b][jj + 1]      + bia1[0];
                float zf1 = zs[b][8 + jj + 1]  + bia1[1];
                float zg1 = zs[b][16 + jj + 1] + bia1[2];
                float zo1 = zs[b][24 + jj + 1] + bia1[3];
                c1 = sigm(zf1) * c1 + sigm(zi1) * tanhf(zg1);
                float h1v = sigm(zo1) * tanhf(c1);
                u16 hb0 = f2bf(h0v), hb1 = f2bf(h1v);
                if (layer) llc_store2(acat  + ((size_t)t * 64 + b) * 544 + jbase + jj, hb0, hb1);
                else       llc_store2(h0seq + ((size_t)t * 64 + b) * 512 + jbase + jj, hb0, hb1);
            }
            __builtin_amdgcn_s_waitcnt(0);
            __syncthreads();
            if (tid == 0)
                ag_store(fown + me * 16, t + 1);
        }
    } else {
        // ======================= trailing scan + inline gate ===============
        const int sb = blk - 128;          // batch
        const int f = tid & 31, rg = tid >> 5;
        float m[4][32];
#pragma unroll
        for (int x = 0; x < 4; x++)
            for (int y = 0; y < 32; y++) m[x][y] = 0.f;
        __shared__ float r1s[32], r2s[32], fis[32], u1s[32], u2s[32];
        __shared__ float red[8][32];
        __shared__ float wred[4];
        __shared__ float gpart[4];
        float wg0 = Wg[2 * tid], wg1 = Wg[2 * tid + 1];
        float bgv = bg[0];
        for (int t = 0; t < 512; t++) {
            // prefetch scan inputs (independent of flags)
            float pre = 0.f;
            {
                size_t base = ((size_t)t * 64 + sb) * 32;
                if (tid < 32) pre = r1[base + tid];
                else if (tid < 64) pre = r2[base + tid - 32];
                else if (tid < 96) pre = fi[base + tid - 64];
                else if (tid < 128) pre = uu1[base + tid - 96];
                else if (tid < 160) pre = uu2[base + tid - 128];
            }
            // wait for layer 1 to publish h1 row t
            if (tid < 64) {
                int* p1 = f1 + tid * 16;
                int it = 0;
                for (;;) {
                    int a = ag_load(p1);
                    if (__all(a >= t + 1)) break;
                    if (++it > 3000000) break;
                    __builtin_amdgcn_s_sleep(1);
                }
            }
            __syncthreads();
            // stage inputs + gate partial
            if (tid < 32) r1s[tid] = pre;
            else if (tid < 64) r2s[tid - 32] = pre;
            else if (tid < 96) fis[tid - 64] = pre;
            else if (tid < 128) u1s[tid - 96] = pre;
            else if (tid < 160) u2s[tid - 128] = pre;
            {
                const u16* hr = acat + ((size_t)t * 64 + sb) * 544;
                u32 hv = *(const u32*)(hr + 2 * tid);
                float gp = bf2f((u16)hv) * wg0 + bf2f((u16)(hv >> 16)) * wg1;
                for (int mk = 1; mk < 64; mk <<= 1) gp += __shfl_xor(gp, mk, 64);
                if ((tid & 63) == 0) gpart[tid >> 6] = gp;
            }
            __syncthreads();
            float gsh = sigm(gpart[0] + gpart[1] + gpart[2] + gpart[3] + bgv + 1.0f);
            float p = 0.f;
#pragma unroll
            for (int rl = 0; rl < 4; rl++) {
                float s = 0.f;
                for (int ti = 0; ti < 32; ti++) s += r2s[ti] * m[rl][ti];
                p += r1s[rg * 4 + rl] * s;
            }
            red[rg][f] = p;
            __syncthreads();
            float prev = 0.f;
#pragma unroll
            for (int g = 0; g < 8; g++) prev += red[g][f];
            float curo = gsh * (fis[f] - prev) * (1.0f / 32.0f);
            float nsq = 0.f;
#pragma unroll
            for (int rl = 0; rl < 4; rl++) {
                float a = r1s[rg * 4 + rl] * curo;
                for (int ti = 0; ti < 32; ti++) {
                    m[rl][ti] += a * r2s[ti];
                    nsq += m[rl][ti] * m[rl][ti];
                }
            }
            for (int mk = 1; mk < 64; mk <<= 1) nsq += __shfl_xor(nsq, mk, 64);
            __syncthreads();
            if ((tid & 63) == 0) wred[tid >> 6] = nsq;
            __syncthreads();
            float nrm = sqrtf(wred[0] + wred[1] + wred[2] + wred[3]);
            float sc = nrm > 1.0f ? 1.0f / nrm : 1.0f;   // relu(nrm-1)+1 == max(nrm,1)
            float rp = 0.f;
#pragma unroll
            for (int rl = 0; rl < 4; rl++) {
                float s = 0.f;
                for (int ti = 0; ti < 32; ti++) {
                    m[rl][ti] *= sc;
                    s += m[rl][ti] * u2s[ti];
                }
                rp += u1s[rg * 4 + rl] * s;
            }
            red[rg][f] = rp;
            __syncthreads();
            float rv = 0.f;
#pragma unroll
            for (int g = 0; g < 8; g++) rv += red[g][f];
            float mean = rv;
            for (int mk = 1; mk < 32; mk <<= 1) mean += __shfl_xor(mean, mk, 32);
            mean *= (1.0f / 32.0f);
            float d = rv - mean;
            float var = d * d;
            for (int mk = 1; mk < 32; mk <<= 1) var += __shfl_xor(var, mk, 32);
            var *= (1.0f / 32.0f);
            if (tid < 32) {
                float y = d * rsqrtf(var + 1e-5f);
                // agent store: no dirty L2 line (false-sharing-safe with h1 cols of next row)
                llc_store_u16(acat + ((size_t)t * 64 + sb) * 544 + 512 + f, f2bf(y));
            }
            __syncthreads();
        }
    }
}

// ---------------------------------------------------------------------------
extern "C" void kernel_launch(void* const* d_in, const int* in_sizes, int n_in,
                              void* d_out, int out_size, void* d_ws, size_t ws_size,
                              hipStream_t stream)
{
    (void)in_sizes; (void)n_in; (void)out_size; (void)ws_size;
    const int*   tokens = (const int*)d_in[0];
    const float* embW  = (const float*)d_in[1];
    const float* Wih0  = (const float*)d_in[2];
    const float* Whh0  = (const float*)d_in[3];
    const float* bih0  = (const float*)d_in[4];
    const float* bhh0  = (const float*)d_in[5];
    const float* Wih1  = (const float*)d_in[6];
    const float* Whh1  = (const float*)d_in[7];
    const float* bih1  = (const float*)d_in[8];
    const float* bhh1  = (const float*)d_in[9];
    const float* Wpi   = (const float*)d_in[10];
    const float* bpi   = (const float*)d_in[11];
    const float* Wq    = (const float*)d_in[12];
    const float* bq    = (const float*)d_in[13];
    const float* Wk    = (const float*)d_in[14];
    const float* bk    = (const float*)d_in[15];
    const float* Wv    = (const float*)d_in[16];
    const float* bv    = (const float*)d_in[17];
    const float* lng   = (const float*)d_in[18];
    const float* lnb   = (const float*)d_in[19];
    const float* Wm1   = (const float*)d_in[20];
    const float* bm1   = (const float*)d_in[21];
    const float* Wm2   = (const float*)d_in[22];
    const float* bm2   = (const float*)d_in[23];
    const float* Wbind = (const float*)d_in[24];
    const float* bbind = (const float*)d_in[25];
    const float* Wreas = (const float*)d_in[26];
    const float* breas = (const float*)d_in[27];
    const float* Wsp   = (const float*)d_in[28];
    const float* bsp   = (const float*)d_in[29];
    const float* Wg    = (const float*)d_in[30];
    const float* bg    = (const float*)d_in[31];
    const float* Wout  = (const float*)d_in[32];
    const float* bout  = (const float*)d_in[33];

    char* ws = (char*)d_ws;
    size_t off = 0;
    auto alloc = [&](size_t bytes) { size_t o = off; off += (bytes + 255) & ~(size_t)255; return o; };
    int*  flags  = (int*)(ws + alloc(2 * 64 * 16 * 4));
    u16*  emb    = (u16*)(ws + alloc(32768ull * 256 * 2));
    u16*  dec    = (u16*)(ws + alloc(32768ull * 192 * 2));
    u16*  initb  = (u16*)(ws + alloc(32768ull * 96 * 2));
    u16*  initr  = (u16*)(ws + alloc(32768ull * 64 * 2));
    u16*  acat   = (u16*)(ws + alloc(32768ull * 544 * 2));
    u16*  h0seq  = (u16*)(ws + alloc(512ull * 64 * 512 * 2));
    float* role1 = (float*)(ws + alloc(32768ull * 32 * 4));
    float* role2 = (float*)(ws + alloc(32768ull * 32 * 4));
    float* fill  = (float*)(ws + alloc(32768ull * 32 * 4));
    float* u1v   = (float*)(ws + alloc(32768ull * 32 * 4));
    float* u2v   = (float*)(ws + alloc(32768ull * 32 * 4));
    u16* Wx0b  = (u16*)(ws + alloc(2048ull * 256 * 2));
    u16* Wh0b  = (u16*)(ws + alloc(2048ull * 512 * 2));
    u16* Wx1b  = (u16*)(ws + alloc(2048ull * 512 * 2));
    u16* Wh1b  = (u16*)(ws + alloc(2048ull * 512 * 2));
    u16* Wpib  = (u16*)(ws + alloc(192ull * 256 * 2));
    u16* Wbindb = (u16*)(ws + alloc(96ull * 192 * 2));
    u16* Wreasb = (u16*)(ws + alloc(64ull * 192 * 2));
    u16* Woutb  = (u16*)(ws + alloc(128ull * 544 * 2));

    hipMemsetAsync(flags, 0, 2 * 64 * 16 * 4, stream);
    {
        Cvt8 c;
        const float* s[8] = {Wih0, Whh0, Wih1, Whh1, Wpi, Wbind, Wreas, Wout};
        u16* d[8] = {Wx0b, Wh0b, Wx1b, Wh1b, Wpib, Wbindb, Wreasb, Woutb};
        int n[8] = {2048 * 256, 2048 * 512, 2048 * 512, 2048 * 512,
                    192 * 256, 96 * 192, 64 * 192, 128 * 544};
        int acc = 0;
        for (int k = 0; k < 8; k++) { c.s[k] = s[k]; c.d[k] = d[k]; c.off4[k] = acc; acc += n[k] / 4; }
        c.off4[8] = acc;
        k_f2b8<<<(acc + 255) / 256, 256, 0, stream>>>(c);
    }
    k_embed<<<4096, 256, 0, stream>>>(tokens, embW, emb);
    k_gemm_bt<<<dim3(256, 2), 256, 0, stream>>>(emb, 256, Wpib, dec, nullptr, 192, bpi, nullptr, 192, 256);
    k_gemm_bt<<<dim3(256, 1), 256, 0, stream>>>(dec, 192, Wbindb, initb, nullptr, 96, bbind, nullptr, 96, 192);
    k_gemm_bt<<<dim3(256, 1), 256, 0, stream>>>(dec, 192, Wreasb, initr, nullptr, 64, breas, nullptr, 64, 192);
    // slot attention (must precede mega: scan consumes its outputs)
    k_slot<3><<<4096, 256, 0, stream>>>(dec, initb, Wq, bq, Wk, bk, Wv, bv, lng, lnb,
                                        Wm1, bm1, Wm2, bm2, Wsp, bsp, role1, role2, fill);
    k_slot<2><<<4096, 256, 0, stream>>>(dec, initr, Wq, bq, Wk, bk, Wv, bv, lng, lnb,
                                        Wm1, bm1, Wm2, bm2, Wsp, bsp, u1v, u2v, nullptr);
    // fused LSTM(2 layers) + trailing scan/gate
    k_mega<<<192, 256, 0, stream>>>(emb, Wx0b, Wh0b, Wx1b, Wh1b,
                                    bih0, bhh0, bih1, bhh1,
                                    h0seq, acat, flags,
                                    role1, role2, fill, u1v, u2v, Wg, bg);
    // out = acat @ Wout^T + bout  (fp32 output)
    k_gemm_bt<<<dim3(256, 1), 256, 0, stream>>>(acat, 544, Woutb, nullptr, (float*)d_out, 128, bout, nullptr, 128, 544);
}

// Round 8
// 4308.046 us; speedup vs baseline: 3.0735x; 1.0629x over previous
//
#include <hip/hip_runtime.h>

typedef unsigned short u16;
typedef unsigned int u32;
typedef unsigned long long u64;
typedef __bf16 bf16x8 __attribute__((ext_vector_type(8)));
typedef float f32x4 __attribute__((ext_vector_type(4)));

__device__ __forceinline__ float bf2f(u16 u) { return __uint_as_float(((u32)u) << 16); }
__device__ __forceinline__ u16 f2bf(float f) {
    u32 u = __float_as_uint(f);
    u32 r = (u + 0x7FFFu + ((u >> 16) & 1u)) >> 16;
    return (u16)r;
}
__device__ __forceinline__ float sigm(float x) { return 1.0f / (1.0f + __expf(-x)); }
__device__ __forceinline__ float elu1(float x) { return x > 0.0f ? x + 1.0f : __expf(x); }

// agent-scope (LLC) atomics — HW-validated cross-XCD path (R5/R7)
__device__ __forceinline__ int ag_load(const int* p) {
    return __hip_atomic_load(p, __ATOMIC_RELAXED, __HIP_MEMORY_SCOPE_AGENT);
}
__device__ __forceinline__ void ag_store(int* p, int v) {
    __hip_atomic_store(p, v, __ATOMIC_RELAXED, __HIP_MEMORY_SCOPE_AGENT);
}
__device__ __forceinline__ void llc_store2(u16* p, u16 a, u16 b) {
    u32 v = (u32)a | ((u32)b << 16);
    __hip_atomic_store((u32*)p, v, __ATOMIC_RELAXED, __HIP_MEMORY_SCOPE_AGENT);
}
__device__ __forceinline__ void llc_store_u16(u16* p, u16 v) {
    __hip_atomic_store(p, v, __ATOMIC_RELAXED, __HIP_MEMORY_SCOPE_AGENT);
}

// ---------------------------------------------------------------------------
struct Cvt8 { const float* s[8]; u16* d[8]; int off4[9]; };

__global__ __launch_bounds__(256) void k_f2b8(Cvt8 c)
{
    int i = blockIdx.x * 256 + threadIdx.x;
    if (i >= c.off4[8]) return;
    int k = 0;
#pragma unroll
    for (int q = 1; q < 8; q++) if (i >= c.off4[q]) k = q;
    int j = i - c.off4[k];
    float4 v = ((const float4*)c.s[k])[j];
    ushort4 o;
    o.x = f2bf(v.x); o.y = f2bf(v.y); o.z = f2bf(v.z); o.w = f2bf(v.w);
    ((ushort4*)c.d[k])[j] = o;
}

// ---------------------------------------------------------------------------
__global__ __launch_bounds__(256) void k_embed(const int* __restrict__ tok,
                                               const float* __restrict__ W,
                                               u16* __restrict__ out)
{
    int c = blockIdx.x * 256 + threadIdx.x;
    int row = c >> 5, cc = (c & 31) * 8;
    int t = tok[row];
    const float* src = W + (size_t)t * 256 + cc;
    u16 tmp[8];
#pragma unroll
    for (int k = 0; k < 8; k++) tmp[k] = f2bf(src[k]);
    *(uint4*)(out + (size_t)row * 256 + cc) = *(uint4*)tmp;
}

// ---------------------------------------------------------------------------
// GEMM:  C[M,N] = A[M,K](bf16, lda) * B[N,K]^T(bf16) + bias. 128x128 tile.
// ---------------------------------------------------------------------------
__global__ __launch_bounds__(256) void k_gemm_bt(
    const u16* __restrict__ A, int lda,
    const u16* __restrict__ B,
    u16* __restrict__ Cb, float* __restrict__ Cf, int ldc,
    const float* __restrict__ bias1, const float* __restrict__ bias2,
    int N, int K)
{
    __shared__ u16 As[128][40];
    __shared__ u16 Bs[128][40];
    const int tid = threadIdx.x;
    const int m0 = blockIdx.x * 128, n0 = blockIdx.y * 128;
    const int wave = tid >> 6, lane = tid & 63;
    const int wm = wave & 1, wn = wave >> 1;
    const int quad = lane >> 4, l16 = lane & 15;
    f32x4 acc[4][4] = {};
    for (int k0 = 0; k0 < K; k0 += 32) {
        __syncthreads();
#pragma unroll
        for (int i = 0; i < 2; i++) {
            int c = tid + i * 256, row = c >> 2, cc = (c & 3) * 8;
            *(uint4*)(&As[row][cc]) = *(const uint4*)(A + (size_t)(m0 + row) * lda + k0 + cc);
            uint4 d = {0, 0, 0, 0};
            if (n0 + row < N) d = *(const uint4*)(B + (size_t)(n0 + row) * K + k0 + cc);
            *(uint4*)(&Bs[row][cc]) = d;
        }
        __syncthreads();
        bf16x8 af[4], bfm[4];
#pragma unroll
        for (int x = 0; x < 4; x++) {
            af[x]  = *(const bf16x8*)(&As[wm * 64 + x * 16 + l16][quad * 8]);
            bfm[x] = *(const bf16x8*)(&Bs[wn * 64 + x * 16 + l16][quad * 8]);
        }
#pragma unroll
        for (int mi = 0; mi < 4; mi++)
#pragma unroll
            for (int ni = 0; ni < 4; ni++)
                acc[mi][ni] = __builtin_amdgcn_mfma_f32_16x16x32_bf16(af[mi], bfm[ni], acc[mi][ni], 0, 0, 0);
    }
#pragma unroll
    for (int ni = 0; ni < 4; ni++) {
        int col = n0 + wn * 64 + ni * 16 + l16;
        if (col < N) {
            float bv = 0.f;
            if (bias1) bv += bias1[col];
            if (bias2) bv += bias2[col];
#pragma unroll
            for (int mi = 0; mi < 4; mi++) {
                int r0 = m0 + wm * 64 + mi * 16 + quad * 4;
#pragma unroll
                for (int r = 0; r < 4; r++) {
                    float v = acc[mi][ni][r] + bv;
                    if (Cb) Cb[(size_t)(r0 + r) * ldc + col] = f2bf(v);
                    else    Cf[(size_t)(r0 + r) * ldc + col] = v;
                }
            }
        }
    }
}

// ---------------------------------------------------------------------------
// Slot attention (standalone, R5-proven). 8 positions/block.
// ---------------------------------------------------------------------------
template <int NSLOT>
__global__ __launch_bounds__(256) void k_slot(
    const u16* __restrict__ dec, const u16* __restrict__ initp,
    const float* __restrict__ Wq, const float* __restrict__ bq,
    const float* __restrict__ Wk, const float* __restrict__ bk,
    const float* __restrict__ Wv, const float* __restrict__ bv,
    const float* __restrict__ lng, const float* __restrict__ lnb,
    const float* __restrict__ Wm1, const float* __restrict__ bm1,
    const float* __restrict__ Wm2, const float* __restrict__ bm2,
    const float* __restrict__ Wsp, const float* __restrict__ bsp,
    float* __restrict__ o1, float* __restrict__ o2, float* __restrict__ o3)
{
    __shared__ float WqT[32][33], WkT[64][33], WvT[64][33], Wm1T[32][65], Wm2T[64][33], WspT[64][33];
    __shared__ float bq_s[32], bk_s[32], bv_s[32], bm1_s[64], bm2_s[32], bsp_s[32], g_s[32], be_s[32];
    __shared__ u16 xbuf[8][192];
    __shared__ float slots[8][3][32], initl[8][3][32], kk[8][3][32], vv[8][3][32], qq[8][3][32];
    __shared__ float att[8][3][4];
    __shared__ float ubuf[8][32];
    __shared__ float hid[8][64];
    const int tid = threadIdx.x;
    for (int i = tid; i < 1024; i += 256) { int o = i >> 5, c = i & 31; WqT[c][o] = Wq[o * 32 + c]; }
    for (int i = tid; i < 2048; i += 256) {
        int o6 = i >> 6, c6 = i & 63;
        WkT[c6][o6]  = Wk[o6 * 64 + c6];
        WvT[c6][o6]  = Wv[o6 * 64 + c6];
        Wm2T[c6][o6] = Wm2[o6 * 64 + c6];
        WspT[c6][o6] = Wsp[o6 * 64 + c6];
        int o5 = i >> 5, c5 = i & 31;
        Wm1T[c5][o5] = Wm1[o5 * 32 + c5];
    }
    if (tid < 32) {
        bq_s[tid] = bq[tid]; bk_s[tid] = bk[tid]; bv_s[tid] = bv[tid];
        bm2_s[tid] = bm2[tid]; bsp_s[tid] = bsp[tid];
        g_s[tid] = lng[tid]; be_s[tid] = lnb[tid];
    }
    if (tid < 64) bm1_s[tid] = bm1[tid];
    const int p = tid >> 5, l = tid & 31;
    const size_t row = (size_t)blockIdx.x * 8 + p;
    for (int i = l; i < 192; i += 32) xbuf[p][i] = dec[row * 192 + i];
    __syncthreads();
#pragma unroll
    for (int i = 0; i < 3; i++) {
        float aK = bk_s[l], aV = bv_s[l];
        for (int c = 0; c < 64; c++) {
            float x = bf2f(xbuf[p][i * 64 + c]);
            aK += x * WkT[c][l];
            aV += x * WvT[c][l];
        }
        kk[p][i][l] = elu1(aK);
        vv[p][i][l] = aV;
    }
#pragma unroll
    for (int j = 0; j < NSLOT; j++) {
        float iv = bf2f(initp[row * (NSLOT * 32) + j * 32 + l]);
        initl[p][j][l] = iv;
        slots[p][j][l] = iv;
    }
    __syncthreads();
    const float rs = 0.17677669529663687f;
    for (int it = 0; it < 3; it++) {
#pragma unroll
        for (int j = 0; j < NSLOT; j++) {
            float a = bq_s[l];
            for (int c = 0; c < 32; c++) a += slots[p][j][c] * WqT[c][l];
            qq[p][j][l] = elu1((a + initl[p][j][l]) * rs);
        }
        __syncthreads();
        if (l < 3 * NSLOT) {
            int i = l / NSLOT, j = l % NSLOT;
            float s = 0.f;
            for (int c = 0; c < 32; c++) s += kk[p][i][c] * qq[p][j][c];
            att[p][i][j] = s;
        }
        __syncthreads();
        if (l < 3) {
            float mx = -1e30f;
            for (int j = 0; j < NSLOT; j++) mx = fmaxf(mx, att[p][l][j]);
            float sm = 0.f, ex[NSLOT];
            for (int j = 0; j < NSLOT; j++) { ex[j] = __expf(att[p][l][j] - mx); sm += ex[j]; }
            for (int j = 0; j < NSLOT; j++) att[p][l][j] = ex[j] / sm + 1e-8f;
        }
        __syncthreads();
        if (l < NSLOT) {
            float s = att[p][0][l] + att[p][1][l] + att[p][2][l];
            float inv = 1.0f / s;
            for (int i = 0; i < 3; i++) att[p][i][l] *= inv;
        }
        __syncthreads();
#pragma unroll
        for (int j = 0; j < NSLOT; j++) {
            float u = att[p][0][j] * vv[p][0][l] + att[p][1][j] * vv[p][1][l] + att[p][2][j] * vv[p][2][l];
            float mean = u;
            for (int mk = 1; mk < 32; mk <<= 1) mean += __shfl_xor(mean, mk, 32);
            mean *= (1.0f / 32.0f);
            float d = u - mean;
            float var = d * d;
            for (int mk = 1; mk < 32; mk <<= 1) var += __shfl_xor(var, mk, 32);
            var *= (1.0f / 32.0f);
            float y = d * rsqrtf(var + 1e-5f) * g_s[l] + be_s[l];
            ubuf[p][l] = y;
            __syncthreads();
#pragma unroll
            for (int oo = 0; oo < 2; oo++) {
                int o = l + oo * 32;
                float a = bm1_s[o];
                for (int c = 0; c < 32; c++) a += ubuf[p][c] * Wm1T[c][o];
                hid[p][o] = fmaxf(a, 0.f);
            }
            __syncthreads();
            float a2 = bm2_s[l];
            for (int c = 0; c < 64; c++) a2 += hid[p][c] * Wm2T[c][l];
            slots[p][j][l] += a2 * (1.0f / 32.0f);
            __syncthreads();
        }
    }
    float pj[NSLOT];
#pragma unroll
    for (int j = 0; j < NSLOT; j++) {
        float a = bsp_s[l];
        for (int c = 0; c < 32; c++) a += initl[p][j][c] * WspT[c][l];
        for (int c = 0; c < 32; c++) a += slots[p][j][c] * WspT[32 + c][l];
        pj[j] = a;
    }
    const float e = 1e-6f, me = (float)(1.0 - 2e-6);
    if (NSLOT == 3) {
        o1[row * 32 + l] = tanhf(me * pj[0] + e * pj[1] + e * pj[2]);
        o2[row * 32 + l] = tanhf(e * pj[0] + me * pj[1] + e * pj[2]);
        o3[row * 32 + l] = tanhf(e * pj[0] + e * pj[1] + me * pj[2]);
    } else {
        o1[row * 32 + l] = tanhf(me * pj[0] + e * pj[1]);
        o2[row * 32 + l] = tanhf(e * pj[0] + me * pj[1]);
    }
}

// ---------------------------------------------------------------------------
// Mega kernel: 192 blocks. Wave-autonomous LSTM: wave w of block j owns
// batches 16w..16w+16 x h-cols 8j..8j+8. NO __syncthreads in the step loop —
// per-wave vmcnt drain + per-wave flags (4 independent batch-group sync
// domains of 64 waves each). Flags: f[layer][group*64+block] stride-16 ints.
//   blocks 0..63   layer 0; 64..127 layer 1; 128..191 trailing scan+gate.
// ---------------------------------------------------------------------------
__global__ __launch_bounds__(256) void k_mega(
    const u16* __restrict__ emb,
    const u16* __restrict__ Wx0, const u16* __restrict__ Wh0,
    const u16* __restrict__ Wx1, const u16* __restrict__ Wh1,
    const float* __restrict__ bi0, const float* __restrict__ bh0,
    const float* __restrict__ bi1, const float* __restrict__ bh1,
    u16* __restrict__ h0seq,        // [512][64][512] write-once
    u16* __restrict__ acat,         // [32768][544]; cols 0..511 h1, 512.. scan out
    int* __restrict__ flags,        // f0 @0 (256x16 ints), f1 @4096
    const float* __restrict__ r1, const float* __restrict__ r2,
    const float* __restrict__ fi, const float* __restrict__ uu1,
    const float* __restrict__ uu2,
    const float* __restrict__ Wg, const float* __restrict__ bg)
{
    const int tid = threadIdx.x;
    const int blk = blockIdx.x;
    int* f0 = flags;
    int* f1 = flags + 4096;

    if (blk < 128) {
        // =================== wave-autonomous LSTM ======================
        __shared__ u16 Wx[32][528];
        __shared__ u16 Wh[32][528];
        __shared__ float zs[4][16][33];
        const int layer = blk >> 6;
        const int me = blk & 63;
        const int jbase = me * 8;
        const int Kx = layer ? 512 : 256;
        const u16* Wxp = layer ? Wx1 : Wx0;
        const u16* Whp = layer ? Wh1 : Wh0;
        const float* bi = layer ? bi1 : bi0;
        const float* bh = layer ? bh1 : bh0;
#pragma unroll
        for (int i = 0; i < 8; i++) {
            int c = tid + i * 256;
            int row = c >> 6, cc = (c & 63) * 8;
            int grow = (row >> 3) * 512 + jbase + (row & 7);
            *(uint4*)(&Wh[row][cc]) = *(const uint4*)(Whp + (size_t)grow * 512 + cc);
        }
        {
            int cpr = Kx >> 3;
            int iters = (32 * cpr) >> 8;
            for (int i = 0; i < iters; i++) {
                int c = tid + i * 256;
                int row = c / cpr, cc = (c % cpr) * 8;
                int grow = (row >> 3) * 512 + jbase + (row & 7);
                *(uint4*)(&Wx[row][cc]) = *(const uint4*)(Wxp + (size_t)grow * Kx + cc);
            }
        }
        const int wave = tid >> 6, lane = tid & 63;
        const int quad = lane >> 4, l16 = lane & 15;
        const int m = wave * 16 + l16;       // global batch row for MFMA A-load
        const int bl = lane >> 2;            // local batch (0..15)
        const int b = wave * 16 + bl;        // global batch for elementwise
        const int jj = (lane & 3) * 2;       // local col pair
        float bia0[4], bia1[4];
#pragma unroll
        for (int g = 0; g < 4; g++) {
            bia0[g] = bi[g * 512 + jbase + jj]     + bh[g * 512 + jbase + jj];
            bia1[g] = bi[g * 512 + jbase + jj + 1] + bh[g * 512 + jbase + jj + 1];
        }
        int* fown = layer ? f1 : f0;
        const int pollOwn = (wave * 64 + lane) * 16;   // lane polls block `lane`, group `wave`
        const int pubIdx  = (wave * 64 + me) * 16;
        float c0 = 0.f, c1 = 0.f;
        __syncthreads();   // Wx/Wh staged; last barrier before the loop
        for (int t = 0; t < 512; t++) {
            f32x4 acc0 = {}, acc1 = {};
            if (!layer) {
                // x-part (emb, independent of flags)
                const u16* xrow = emb + ((size_t)t * 64 + m) * 256;
#pragma unroll
                for (int kc = 0; kc < 8; kc++) {
                    bf16x8 a  = *(const bf16x8*)(xrow + kc * 32 + quad * 8);
                    bf16x8 w0 = *(const bf16x8*)(&Wx[l16][kc * 32 + quad * 8]);
                    bf16x8 w1 = *(const bf16x8*)(&Wx[16 + l16][kc * 32 + quad * 8]);
                    acc0 = __builtin_amdgcn_mfma_f32_16x16x32_bf16(a, w0, acc0, 0, 0, 0);
                    acc1 = __builtin_amdgcn_mfma_f32_16x16x32_bf16(a, w1, acc1, 0, 0, 0);
                }
                if (t > 0) {   // wait for group-w h0[t-1]
                    int it = 0;
                    for (;;) {
                        int a = ag_load(f0 + pollOwn);
                        if (__all(a >= t)) break;
                        if (++it > 3000000) break;
                        __builtin_amdgcn_s_sleep(1);
                    }
                    const u16* hrd = h0seq + ((size_t)(t - 1) * 64 + m) * 512;
#pragma unroll
                    for (int kc = 0; kc < 16; kc++) {
                        bf16x8 a  = *(const bf16x8*)(hrd + kc * 32 + quad * 8);
                        bf16x8 w0 = *(const bf16x8*)(&Wh[l16][kc * 32 + quad * 8]);
                        bf16x8 w1 = *(const bf16x8*)(&Wh[16 + l16][kc * 32 + quad * 8]);
                        acc0 = __builtin_amdgcn_mfma_f32_16x16x32_bf16(a, w0, acc0, 0, 0, 0);
                        acc1 = __builtin_amdgcn_mfma_f32_16x16x32_bf16(a, w1, acc1, 0, 0, 0);
                    }
                }
            } else {
                // wait for h0[t] (f0 group w >= t+1), then x-part
                {
                    int it = 0;
                    for (;;) {
                        int a = ag_load(f0 + pollOwn);
                        if (__all(a >= t + 1)) break;
                        if (++it > 3000000) break;
                        __builtin_amdgcn_s_sleep(1);
                    }
                }
                const u16* xrow = h0seq + ((size_t)t * 64 + m) * 512;
#pragma unroll
                for (int kc = 0; kc < 16; kc++) {
                    bf16x8 a  = *(const bf16x8*)(xrow + kc * 32 + quad * 8);
                    bf16x8 w0 = *(const bf16x8*)(&Wx[l16][kc * 32 + quad * 8]);
                    bf16x8 w1 = *(const bf16x8*)(&Wx[16 + l16][kc * 32 + quad * 8]);
                    acc0 = __builtin_amdgcn_mfma_f32_16x16x32_bf16(a, w0, acc0, 0, 0, 0);
                    acc1 = __builtin_amdgcn_mfma_f32_16x16x32_bf16(a, w1, acc1, 0, 0, 0);
                }
                if (t > 0) {   // wait for group-w h1[t-1], then h-part
                    int it = 0;
                    for (;;) {
                        int a = ag_load(f1 + pollOwn);
                        if (__all(a >= t)) break;
                        if (++it > 3000000) break;
                        __builtin_amdgcn_s_sleep(1);
                    }
                    const u16* hrd = acat + ((size_t)(t - 1) * 64 + m) * 544;
#pragma unroll
                    for (int kc = 0; kc < 16; kc++) {
                        bf16x8 a  = *(const bf16x8*)(hrd + kc * 32 + quad * 8);
                        bf16x8 w0 = *(const bf16x8*)(&Wh[l16][kc * 32 + quad * 8]);
                        bf16x8 w1 = *(const bf16x8*)(&Wh[16 + l16][kc * 32 + quad * 8]);
                        acc0 = __builtin_amdgcn_mfma_f32_16x16x32_bf16(a, w0, acc0, 0, 0, 0);
                        acc1 = __builtin_amdgcn_mfma_f32_16x16x32_bf16(a, w1, acc1, 0, 0, 0);
                    }
                }
            }
            // wave-local z staging (no barrier: same-wave LDS, lgkmcnt only)
#pragma unroll
            for (int r = 0; r < 4; r++) {
                zs[wave][quad * 4 + r][l16]      = acc0[r];
                zs[wave][quad * 4 + r][16 + l16] = acc1[r];
            }
            {
                float zi0 = zs[wave][bl][jj]      + bia0[0];
                float zf0 = zs[wave][bl][8 + jj]  + bia0[1];
                float zg0 = zs[wave][bl][16 + jj] + bia0[2];
                float zo0 = zs[wave][bl][24 + jj] + bia0[3];
                c0 = sigm(zf0) * c0 + sigm(zi0) * tanhf(zg0);
                float h0v = sigm(zo0) * tanhf(c0);
                float zi1 = zs[wave][bl][jj + 1]      + bia1[0];
                float zf1 = zs[wave][bl][8 + jj + 1]  + bia1[1];
                float zg1 = zs[wave][bl][16 + jj + 1] + bia1[2];
                float zo1 = zs[wave][bl][24 + jj + 1] + bia1[3];
                c1 = sigm(zf1) * c1 + sigm(zi1) * tanhf(zg1);
                float h1v = sigm(zo1) * tanhf(c1);
                u16 hb0 = f2bf(h0v), hb1 = f2bf(h1v);
                if (layer) llc_store2(acat  + ((size_t)t * 64 + b) * 544 + jbase + jj, hb0, hb1);
                else       llc_store2(h0seq + ((size_t)t * 64 + b) * 512 + jbase + jj, hb0, hb1);
            }
            __builtin_amdgcn_s_waitcnt(0);   // per-WAVE drain: this wave's store acked at LLC
            if (lane == 0)
                ag_store(fown + pubIdx, t + 1);
        }
    } else {
        // =================== trailing scan + inline gate ==================
        const int sb = blk - 128;          // batch
        const int grp = sb >> 4;           // its batch group
        const int f = tid & 31, rg = tid >> 5;
        float m[4][32];
#pragma unroll
        for (int x = 0; x < 4; x++)
            for (int y = 0; y < 32; y++) m[x][y] = 0.f;
        __shared__ float r1s[32], r2s[32], fis[32], u1s[32], u2s[32];
        __shared__ float red[8][32];
        __shared__ float wred[4];
        __shared__ float gpart[4];
        float wg0 = Wg[2 * tid], wg1 = Wg[2 * tid + 1];
        float bgv = bg[0];
        for (int t = 0; t < 512; t++) {
            float pre = 0.f;
            {
                size_t base = ((size_t)t * 64 + sb) * 32;
                if (tid < 32) pre = r1[base + tid];
                else if (tid < 64) pre = r2[base + tid - 32];
                else if (tid < 96) pre = fi[base + tid - 64];
                else if (tid < 128) pre = uu1[base + tid - 96];
                else if (tid < 160) pre = uu2[base + tid - 128];
            }
            if (tid < 64) {   // wait for h1[t] of this batch group
                int* p1 = f1 + (grp * 64 + tid) * 16;
                int it = 0;
                for (;;) {
                    int a = ag_load(p1);
                    if (__all(a >= t + 1)) break;
                    if (++it > 3000000) break;
                    __builtin_amdgcn_s_sleep(1);
                }
            }
            __syncthreads();
            if (tid < 32) r1s[tid] = pre;
            else if (tid < 64) r2s[tid - 32] = pre;
            else if (tid < 96) fis[tid - 64] = pre;
            else if (tid < 128) u1s[tid - 96] = pre;
            else if (tid < 160) u2s[tid - 128] = pre;
            {
                const u16* hr = acat + ((size_t)t * 64 + sb) * 544;
                u32 hv = *(const u32*)(hr + 2 * tid);
                float gp = bf2f((u16)hv) * wg0 + bf2f((u16)(hv >> 16)) * wg1;
                for (int mk = 1; mk < 64; mk <<= 1) gp += __shfl_xor(gp, mk, 64);
                if ((tid & 63) == 0) gpart[tid >> 6] = gp;
            }
            __syncthreads();
            float gsh = sigm(gpart[0] + gpart[1] + gpart[2] + gpart[3] + bgv + 1.0f);
            float p = 0.f;
#pragma unroll
            for (int rl = 0; rl < 4; rl++) {
                float s = 0.f;
                for (int ti = 0; ti < 32; ti++) s += r2s[ti] * m[rl][ti];
                p += r1s[rg * 4 + rl] * s;
            }
            red[rg][f] = p;
            __syncthreads();
            float prev = 0.f;
#pragma unroll
            for (int g = 0; g < 8; g++) prev += red[g][f];
            float curo = gsh * (fis[f] - prev) * (1.0f / 32.0f);
            float nsq = 0.f;
#pragma unroll
            for (int rl = 0; rl < 4; rl++) {
                float a = r1s[rg * 4 + rl] * curo;
                for (int ti = 0; ti < 32; ti++) {
                    m[rl][ti] += a * r2s[ti];
                    nsq += m[rl][ti] * m[rl][ti];
                }
            }
            for (int mk = 1; mk < 64; mk <<= 1) nsq += __shfl_xor(nsq, mk, 64);
            __syncthreads();
            if ((tid & 63) == 0) wred[tid >> 6] = nsq;
            __syncthreads();
            float nrm = sqrtf(wred[0] + wred[1] + wred[2] + wred[3]);
            float sc = nrm > 1.0f ? 1.0f / nrm : 1.0f;   // relu(nrm-1)+1 == max(nrm,1)
            float rp = 0.f;
#pragma unroll
            for (int rl = 0; rl < 4; rl++) {
                float s = 0.f;
                for (int ti = 0; ti < 32; ti++) {
                    m[rl][ti] *= sc;
                    s += m[rl][ti] * u2s[ti];
                }
                rp += u1s[rg * 4 + rl] * s;
            }
            red[rg][f] = rp;
            __syncthreads();
            float rv = 0.f;
#pragma unroll
            for (int g = 0; g < 8; g++) rv += red[g][f];
            float mean = rv;
            for (int mk = 1; mk < 32; mk <<= 1) mean += __shfl_xor(mean, mk, 32);
            mean *= (1.0f / 32.0f);
            float d = rv - mean;
            float var = d * d;
            for (int mk = 1; mk < 32; mk <<= 1) var += __shfl_xor(var, mk, 32);
            var *= (1.0f / 32.0f);
            if (tid < 32) {
                float y = d * rsqrtf(var + 1e-5f);
                llc_store_u16(acat + ((size_t)t * 64 + sb) * 544 + 512 + f, f2bf(y));
            }
            __syncthreads();
        }
    }
}

// ---------------------------------------------------------------------------
extern "C" void kernel_launch(void* const* d_in, const int* in_sizes, int n_in,
                              void* d_out, int out_size, void* d_ws, size_t ws_size,
                              hipStream_t stream)
{
    (void)in_sizes; (void)n_in; (void)out_size; (void)ws_size;
    const int*   tokens = (const int*)d_in[0];
    const float* embW  = (const float*)d_in[1];
    const float* Wih0  = (const float*)d_in[2];
    const float* Whh0  = (const float*)d_in[3];
    const float* bih0  = (const float*)d_in[4];
    const float* bhh0  = (const float*)d_in[5];
    const float* Wih1  = (const float*)d_in[6];
    const float* Whh1  = (const float*)d_in[7];
    const float* bih1  = (const float*)d_in[8];
    const float* bhh1  = (const float*)d_in[9];
    const float* Wpi   = (const float*)d_in[10];
    const float* bpi   = (const float*)d_in[11];
    const float* Wq    = (const float*)d_in[12];
    const float* bq    = (const float*)d_in[13];
    const float* Wk    = (const float*)d_in[14];
    const float* bk    = (const float*)d_in[15];
    const float* Wv    = (const float*)d_in[16];
    const float* bv    = (const float*)d_in[17];
    const float* lng   = (const float*)d_in[18];
    const float* lnb   = (const float*)d_in[19];
    const float* Wm1   = (const float*)d_in[20];
    const float* bm1   = (const float*)d_in[21];
    const float* Wm2   = (const float*)d_in[22];
    const float* bm2   = (const float*)d_in[23];
    const float* Wbind = (const float*)d_in[24];
    const float* bbind = (const float*)d_in[25];
    const float* Wreas = (const float*)d_in[26];
    const float* breas = (const float*)d_in[27];
    const float* Wsp   = (const float*)d_in[28];
    const float* bsp   = (const float*)d_in[29];
    const float* Wg    = (const float*)d_in[30];
    const float* bg    = (const float*)d_in[31];
    const float* Wout  = (const float*)d_in[32];
    const float* bout  = (const float*)d_in[33];

    char* ws = (char*)d_ws;
    size_t off = 0;
    auto alloc = [&](size_t bytes) { size_t o = off; off += (bytes + 255) & ~(size_t)255; return o; };
    int*  flags  = (int*)(ws + alloc(2 * 4096 * 4));
    u16*  emb    = (u16*)(ws + alloc(32768ull * 256 * 2));
    u16*  dec    = (u16*)(ws + alloc(32768ull * 192 * 2));
    u16*  initb  = (u16*)(ws + alloc(32768ull * 96 * 2));
    u16*  initr  = (u16*)(ws + alloc(32768ull * 64 * 2));
    u16*  acat   = (u16*)(ws + alloc(32768ull * 544 * 2));
    u16*  h0seq  = (u16*)(ws + alloc(512ull * 64 * 512 * 2));
    float* role1 = (float*)(ws + alloc(32768ull * 32 * 4));
    float* role2 = (float*)(ws + alloc(32768ull * 32 * 4));
    float* fill  = (float*)(ws + alloc(32768ull * 32 * 4));
    float* u1v   = (float*)(ws + alloc(32768ull * 32 * 4));
    float* u2v   = (float*)(ws + alloc(32768ull * 32 * 4));
    u16* Wx0b  = (u16*)(ws + alloc(2048ull * 256 * 2));
    u16* Wh0b  = (u16*)(ws + alloc(2048ull * 512 * 2));
    u16* Wx1b  = (u16*)(ws + alloc(2048ull * 512 * 2));
    u16* Wh1b  = (u16*)(ws + alloc(2048ull * 512 * 2));
    u16* Wpib  = (u16*)(ws + alloc(192ull * 256 * 2));
    u16* Wbindb = (u16*)(ws + alloc(96ull * 192 * 2));
    u16* Wreasb = (u16*)(ws + alloc(64ull * 192 * 2));
    u16* Woutb  = (u16*)(ws + alloc(128ull * 544 * 2));

    hipMemsetAsync(flags, 0, 2 * 4096 * 4, stream);
    {
        Cvt8 c;
        const float* s[8] = {Wih0, Whh0, Wih1, Whh1, Wpi, Wbind, Wreas, Wout};
        u16* d[8] = {Wx0b, Wh0b, Wx1b, Wh1b, Wpib, Wbindb, Wreasb, Woutb};
        int n[8] = {2048 * 256, 2048 * 512, 2048 * 512, 2048 * 512,
                    192 * 256, 96 * 192, 64 * 192, 128 * 544};
        int acc = 0;
        for (int k = 0; k < 8; k++) { c.s[k] = s[k]; c.d[k] = d[k]; c.off4[k] = acc; acc += n[k] / 4; }
        c.off4[8] = acc;
        k_f2b8<<<(acc + 255) / 256, 256, 0, stream>>>(c);
    }
    k_embed<<<4096, 256, 0, stream>>>(tokens, embW, emb);
    k_gemm_bt<<<dim3(256, 2), 256, 0, stream>>>(emb, 256, Wpib, dec, nullptr, 192, bpi, nullptr, 192, 256);
    k_gemm_bt<<<dim3(256, 1), 256, 0, stream>>>(dec, 192, Wbindb, initb, nullptr, 96, bbind, nullptr, 96, 192);
    k_gemm_bt<<<dim3(256, 1), 256, 0, stream>>>(dec, 192, Wreasb, initr, nullptr, 64, breas, nullptr, 64, 192);
    // slot attention (must precede mega: scan consumes its outputs)
    k_slot<3><<<4096, 256, 0, stream>>>(dec, initb, Wq, bq, Wk, bk, Wv, bv, lng, lnb,
                                        Wm1, bm1, Wm2, bm2, Wsp, bsp, role1, role2, fill);
    k_slot<2><<<4096, 256, 0, stream>>>(dec, initr, Wq, bq, Wk, bk, Wv, bv, lng, lnb,
                                        Wm1, bm1, Wm2, bm2, Wsp, bsp, u1v, u2v, nullptr);
    // fused LSTM(2 layers) + trailing scan/gate, wave-autonomous sync
    k_mega<<<192, 256, 0, stream>>>(emb, Wx0b, Wh0b, Wx1b, Wh1b,
                                    bih0, bhh0, bih1, bhh1,
                                    h0seq, acat, flags,
                                    role1, role2, fill, u1v, u2v, Wg, bg);
    // out = acat @ Wout^T + bout  (fp32 output)
    k_gemm_bt<<<dim3(256, 1), 256, 0, stream>>>(acat, 544, Woutb, nullptr, (float*)d_out, 128, bout, nullptr, 128, 544);
}